// Round 15
// baseline (297.025 us; speedup 1.0000x reference)
//
#include <hip/hip_runtime.h>

typedef __attribute__((ext_vector_type(8))) short bf16x8;
typedef __attribute__((ext_vector_type(4))) float f32x4;
typedef __attribute__((ext_vector_type(8))) unsigned short ushort8;
typedef __attribute__((ext_vector_type(4))) unsigned short ushort4v;
typedef __attribute__((ext_vector_type(4))) float float4v;
typedef __attribute__((ext_vector_type(2))) unsigned int uint2v;
typedef __attribute__((ext_vector_type(4))) unsigned int uint4v;

#define TGT 256
#define BSZ 64
#define EMB 1024
#define NH 16
#define HD 64
#define PP 16

__device__ __forceinline__ float b2f(unsigned short u) {
  return __builtin_bit_cast(float, ((unsigned int)u) << 16);
}
__device__ __forceinline__ unsigned short f2b(float f) {
  unsigned int u = __builtin_bit_cast(unsigned int, f);
  u += 0x7fffu + ((u >> 16) & 1u);  // RNE; no NaNs in this workload
  return (unsigned short)(u >> 16);
}
__device__ __forceinline__ unsigned int pack2(float lo, float hi) {
  return (unsigned int)f2b(lo) | ((unsigned int)f2b(hi) << 16);
}
__device__ __forceinline__ f32x4 mfma16(bf16x8 a, bf16x8 b, f32x4 c) {
  return __builtin_amdgcn_mfma_f32_16x16x32_bf16(a, b, c, 0, 0, 0);
}
// async global->LDS, 16B per lane; LDS dest is wave-uniform base + lane*16
__device__ __forceinline__ void gl_lds16(const unsigned short* g, unsigned short* l) {
  __builtin_amdgcn_global_load_lds(
      (const __attribute__((address_space(1))) unsigned int*)g,
      (__attribute__((address_space(3))) unsigned int*)l, 16, 0, 0);
}

// ---------------------------------------------------------------------------
// Gate: g1[b] = softmax((feat[b]@gw.T + gb + noise[b]) / 3)[1]
// ---------------------------------------------------------------------------
__global__ __launch_bounds__(64) void gate_kernel(
    const float* __restrict__ feat, const float* __restrict__ gw,
    const float* __restrict__ gb, const float* __restrict__ noise,
    float* __restrict__ g1) {
  const int b = blockIdx.x, lane = threadIdx.x;
  float a0 = 0.f, a1 = 0.f;
  for (int i = lane; i < 512; i += 64) {
    float f = feat[b * 512 + i];
    a0 += f * gw[i];
    a1 += f * gw[512 + i];
  }
#pragma unroll
  for (int off = 32; off >= 1; off >>= 1) {
    a0 += __shfl_xor(a0, off);
    a1 += __shfl_xor(a1, off);
  }
  if (lane == 0) {
    float l0 = (a0 + gb[0] + noise[b * 2 + 0]) * (1.0f / 3.0f);
    float l1 = (a1 + gb[1] + noise[b * 2 + 1]) * (1.0f / 3.0f);
    float mm = fmaxf(l0, l1);
    float e0 = __expf(l0 - mm), e1 = __expf(l1 - mm);
    g1[b] = e1 / (e0 + e1);
  }
}

// ---------------------------------------------------------------------------
// f32 -> bf16 cast, 8 elems/thread, grid-stride (weights only)
// ---------------------------------------------------------------------------
__global__ __launch_bounds__(256) void cast_bf16_kernel(
    const float* __restrict__ in, unsigned short* __restrict__ out, int n8) {
  int i = blockIdx.x * blockDim.x + threadIdx.x;
  const int stride = gridDim.x * blockDim.x;
  for (; i < n8; i += stride) {
    const float4v* p = (const float4v*)(in + (size_t)i * 8);
    float4v v0 = p[0], v1 = p[1];
    ushort8 o = {f2b(v0[0]), f2b(v0[1]), f2b(v0[2]), f2b(v0[3]),
                 f2b(v1[0]), f2b(v1[1]), f2b(v1[2]), f2b(v1[3])};
    *(ushort8*)(out + (size_t)i * 8) = o;
  }
}

#define STEP_WAIT(cntstr)                                \
  asm volatile("s_waitcnt " cntstr ::: "memory");        \
  __builtin_amdgcn_sched_barrier(0);                     \
  __builtin_amdgcn_s_barrier();

// ---------------------------------------------------------------------------
// proj: C_bf16_headblocked = A_f32 @ W^T + bias. 256x256, 8 waves, BK=32.
// R15 FRAG-PREFETCH pipeline: during step s, A(s+1)-frags are read from LDS
// into the opposite half of a parity double-buffer (af[2][8]) so step s+1's
// MFMAs start right after the barrier. Enabled by issue-lead-3/write-lead-2:
//   step s: ISSUE_A(s+3) regs; STAGE_B(s+3) gl_lds; MFMA(af[s&1], B(s));
//           prefetch af[(s+1)&1] = A(s+1)-frags;  WRITE_A(s+2) (f2b+ds_write)
// A-LDS = 4-ring. A(s+1) was LDS-written at end of step s-1 and published by
// that barrier -> prefetch-safe. B(s) completion: the compiler-exact vmcnt
// before each f2b drains A-regs(s+2) and all OLDER ops (oldest-first, m135),
// which includes B(s+2) not but B(s+1),B(s) yes -- so B(s) has been complete
// since end of step s-2. Steady outstanding after compiler wait =
// {B(s+2),A(s+3),B(s+3)} = 8 -> manual vmcnt(8) is a no-op backstop.
// Ring overwrite audit: ds_write slot (s+2)&3 last prefetch-read in step
// s-3 (3 barriers); reg slot (s+3)&1 last consumed by f2b at end of s+1? --
// reg ring ar[2][4]: issue (s+3)&1 at s; f2b of (s+2)&1 at end of s; slot
// (s+3)&1=(s+1)&1 was f2b'd at end of s-1 (1 barrier before reissue) OK.
// ---------------------------------------------------------------------------
#define PJ_ISSUE(t, P)                                   \
  {                                                      \
    const float* _p = a32p + (size_t)(t) * 32;           \
    ar[P][0] = *(const float4v*)_p;                      \
    ar[P][1] = *(const float4v*)(_p + 4);                \
    ar[P][2] = *(const float4v*)(_p + 131072);           \
    ar[P][3] = *(const float4v*)(_p + 131072 + 4);       \
  }
#define PJ_WRITE(t, P)                                                  \
  {                                                                     \
    float4v* v = ar[P];                                                 \
    uint4v h0 = {pack2(v[0][0], v[0][1]), pack2(v[0][2], v[0][3]),      \
                 pack2(v[1][0], v[1][1]), pack2(v[1][2], v[1][3])};     \
    uint4v h1 = {pack2(v[2][0], v[2][1]), pack2(v[2][2], v[2][3]),      \
                 pack2(v[3][0], v[3][1]), pack2(v[3][2], v[3][3])};     \
    unsigned short* d = &As[(t) & 3][swA];                              \
    *(uint4v*)d = h0;                                                   \
    *(uint4v*)(d + 4096) = h1;                                          \
  }
#define PJ_STAGE_B(s, SL)                                \
  {                                                      \
    int k0s = (s) * 32;                                  \
    unsigned short* d = &Bs[SL][wl];                     \
    gl_lds16(b0p + k0s, d);                              \
    gl_lds16(b1p + k0s, d + 4096);                       \
  }
#define PJ_PF_A(s, FP)                                                \
  {                                                                   \
    const unsigned short* Ap = &As[(s) & 3][0];                       \
    _Pragma("unroll") for (int mi = 0; mi < 8; ++mi)                  \
        af[FP][mi] = *(const bf16x8*)&Ap[aoff + mi * 512];            \
  }
// s: step; FC=s&1 (cur frag); BS=s&3 (B slot); RP=(s+3)&1 (reg slot)
#define PJ_STEP(s, FC, BS, RP, DO_IA, DO_SB, DO_W, DO_PF)             \
  {                                                                   \
    const unsigned short* Bb = &Bs[BS][0];                            \
    bf16x8 bfr[4];                                                    \
    _Pragma("unroll") for (int ni = 0; ni < 4; ++ni)                  \
        bfr[ni] = *(const bf16x8*)&Bb[boff + ni * 512];               \
    if (DO_IA) PJ_ISSUE((s) + 3, RP);                                 \
    if (DO_SB) PJ_STAGE_B((s) + 3, ((BS) + 3) & 3);                   \
    if (DO_PF) PJ_PF_A((s) + 1, (FC) ^ 1);                            \
    __builtin_amdgcn_s_setprio(1);                                    \
    _Pragma("unroll") for (int mi = 0; mi < 8; ++mi)                  \
      _Pragma("unroll") for (int ni = 0; ni < 4; ++ni)                \
        acc[mi][ni] = mfma16(af[FC][mi], bfr[ni], acc[mi][ni]);       \
    __builtin_amdgcn_s_setprio(0);                                    \
    if (DO_W) PJ_WRITE((s) + 2, (RP) ^ 1); /* A(s+2), reg (s+2)&1 */  \
  }

template <int QSCALE>
__global__ __launch_bounds__(512, 2) void proj_kernel(
    const float* __restrict__ A, const unsigned short* __restrict__ W,
    const float* __restrict__ bias, unsigned short* __restrict__ Cv) {
  constexpr int K = 1024;
  __shared__ __attribute__((aligned(16))) unsigned short As[4][8192];  // 64 KB
  __shared__ __attribute__((aligned(16))) unsigned short Bs[4][8192];  // 64 KB
  const int tid = threadIdx.x;
  const int wv = tid >> 6, lane = tid & 63;
  const int l15 = lane & 15, kg = lane >> 4;
  const int bid = blockIdx.x;
  const int cpx = gridDim.x >> 3;
  const int wg = (bid & 7) * cpx + (bid >> 3);
  const int m0 = (wg >> 2) * 256, n0 = (wg & 3) * 256;
  const int wmL = (wv >> 2) * 128, wnL = (wv & 3) * 64;

  const int sr = wv * 16 + (lane >> 2);                      // row in 128-half
  const int sc = ((lane & 3) * 8) ^ (((sr >> 1) & 3) << 3);  // pre-swizzled col
  const float* a32p = A + (size_t)(m0 + sr) * K + (lane & 3) * 8;
  const int swA = sr * 32 + (((lane & 3) ^ ((sr >> 1) & 3)) << 3);
  float4v ar[2][4];   // reg ring (literal-indexed)
  bf16x8 af[2][8];    // A-frag double buffer (parity-indexed)
  const unsigned short* b0p = W + (size_t)(n0 + sr) * K + sc;
  const unsigned short* b1p = b0p + (size_t)128 * K;
  const int wl = wv * 512;

  const int x = ((l15 >> 1) & 3) << 3;
  const int aoff = (wmL + l15) * 32 + ((kg * 8) ^ x);
  const int boff = (wnL + l15) * 32 + ((kg * 8) ^ x);

  f32x4 acc[8][4];
#pragma unroll
  for (int i = 0; i < 8; ++i)
#pragma unroll
    for (int j = 0; j < 4; ++j) acc[i][j] = (f32x4){0.f, 0.f, 0.f, 0.f};

  // Prologue: A(0),B(0),A(1),B(1),B(2); write A(0),A(1); issue A(2).
  // Each PJ_WRITE's compiler wait drains its A-regs + all older (B(0) by
  // the A(1)-write). After: outstanding {B(1),B(2),A(2)} = 8.
  PJ_ISSUE(0, 0); PJ_STAGE_B(0, 0); PJ_ISSUE(1, 1); PJ_STAGE_B(1, 1);
  PJ_STAGE_B(2, 2);
  PJ_WRITE(0, 0);
  PJ_ISSUE(2, 0);
  PJ_WRITE(1, 1);
  STEP_WAIT("vmcnt(8) lgkmcnt(0)")
  PJ_PF_A(0, 0);  // af[0] = A(0)-frags

  // steps 0..27 rolled (period 4); step s: FC=s&1, BS=s&3, RP=(s+3)&1
#pragma unroll 1
  for (int sb = 0; sb < 28; sb += 4) {
    PJ_STEP(sb + 0, 0, 0, 1, 1, 1, 1, 1);
    STEP_WAIT("vmcnt(8) lgkmcnt(0)")
    PJ_STEP(sb + 1, 1, 1, 0, 1, 1, 1, 1);
    STEP_WAIT("vmcnt(8) lgkmcnt(0)")
    PJ_STEP(sb + 2, 0, 2, 1, 1, 1, 1, 1);
    STEP_WAIT("vmcnt(8) lgkmcnt(0)")
    PJ_STEP(sb + 3, 1, 3, 0, 1, 1, 1, 1);
    STEP_WAIT("vmcnt(8) lgkmcnt(0)")
  }
  // Tail 28..31. 28: issue A(31), stage B(31), write A(30), pf A(29).
  PJ_STEP(28, 0, 0, 1, 1, 1, 1, 1);
  STEP_WAIT("vmcnt(8) lgkmcnt(0)")
  // 29: no issue/stage; write A(31) (regs issued @28); pf A(30).
  PJ_STEP(29, 1, 1, 0, 0, 0, 1, 1);
  STEP_WAIT("vmcnt(8) lgkmcnt(0)")
  // 30: no write; pf A(31) (LDS-written end of 29). End: vmcnt(0) forces
  // B(31) (staged @28 after ISSUE_A(31), so not drained by 29's compiler
  // wait) complete before step 31 reads its frags.
  PJ_STEP(30, 0, 2, 1, 0, 0, 0, 1);
  STEP_WAIT("vmcnt(0) lgkmcnt(0)")
  PJ_STEP(31, 1, 3, 0, 0, 0, 0, 0);

#pragma unroll
  for (int mi = 0; mi < 8; ++mi) {
#pragma unroll
    for (int ni = 0; ni < 4; ++ni) {
      int col = n0 + wnL + ni * 16 + l15;
      float bcol = bias[col];
#pragma unroll
      for (int r = 0; r < 4; ++r) {
        int row = m0 + wmL + mi * 16 + kg * 4 + r;
        float v = acc[mi][ni][r] + bcol;
        if constexpr (QSCALE) v *= 0.125f;
        int t = row >> 6, bb = row & 63, hh = col >> 6, dd = col & 63;
        Cv[(size_t)((bb * 16 + hh) * 256 + t) * 64 + dd] = f2b(v);
      }
    }
  }
}

// ---------------------------------------------------------------------------
// outproj: C_f32 = A_bf16_headblocked @ W^T + b. Same frag-prefetch pipeline;
// A,B both gl_lds lead-3 4-ring; BOTH frag sets double-buffered. All
// completion is manual: steady vmcnt(4) at step end forces AB(s+1) complete
// (leaving AB(s+2) in flight) so step s's prefetch of AB(s+1)-frags is safe.
// Ring overwrite: stage slot (s+3)&3=(s-1)&3, last prefetch-read in step
// s-2 (2 barriers). Tails: end-28 vmcnt(4); end-29 vmcnt(0) (AB(31) for
// step-30 prefetch); end-30 no-op.
// ---------------------------------------------------------------------------
#define OP_AOFF(s) (((s) >> 1) * 16384 + ((s)&1) * 32)
#define OP_STAGE(s, SL)                                  \
  {                                                      \
    const unsigned short* _ap = abf + OP_AOFF(s);        \
    unsigned short* da = &As[SL][wl];                    \
    gl_lds16(_ap, da);                                   \
    gl_lds16(_ap + 128, da + 4096);                      \
    int k0s = (s) * 32;                                  \
    unsigned short* db = &Bs[SL][wl];                    \
    gl_lds16(b0p + k0s, db);                             \
    gl_lds16(b1p + k0s, db + 4096);                      \
  }
#define OP_PF(s, FP)                                                  \
  {                                                                   \
    const unsigned short* Ap = &As[(s) & 3][0];                       \
    const unsigned short* Bp = &Bs[(s) & 3][0];                       \
    _Pragma("unroll") for (int mi = 0; mi < 8; ++mi)                  \
        af[FP][mi] = *(const bf16x8*)&Ap[aoff + mi * 512];            \
    _Pragma("unroll") for (int ni = 0; ni < 4; ++ni)                  \
        bfr[FP][ni] = *(const bf16x8*)&Bp[boff + ni * 512];           \
  }
#define OP_STEP(s, FC, BS, DO_SG, DO_PF)                              \
  {                                                                   \
    if (DO_SG) OP_STAGE((s) + 3, ((BS) + 3) & 3);                     \
    if (DO_PF) OP_PF((s) + 1, (FC) ^ 1);                              \
    __builtin_amdgcn_s_setprio(1);                                    \
    _Pragma("unroll") for (int mi = 0; mi < 8; ++mi)                  \
      _Pragma("unroll") for (int ni = 0; ni < 4; ++ni)                \
        acc[mi][ni] = mfma16(af[FC][mi], bfr[FC][ni], acc[mi][ni]);   \
    __builtin_amdgcn_s_setprio(0);                                    \
  }

__global__ __launch_bounds__(512, 2) void outproj_kernel(
    const unsigned short* __restrict__ A, const unsigned short* __restrict__ W,
    const float* __restrict__ bias, float* __restrict__ Cv) {
  constexpr int K = 1024, N = 1024;
  __shared__ __attribute__((aligned(16))) unsigned short As[4][8192];  // 64 KB
  __shared__ __attribute__((aligned(16))) unsigned short Bs[4][8192];  // 64 KB
  const int tid = threadIdx.x;
  const int wv = tid >> 6, lane = tid & 63;
  const int l15 = lane & 15, kg = lane >> 4;
  const int bid = blockIdx.x;
  const int cpx = gridDim.x >> 3;
  const int wg = (bid & 7) * cpx + (bid >> 3);
  const int m0 = (wg >> 2) * 256, n0 = (wg & 3) * 256;
  const int wmL = (wv >> 2) * 128, wnL = (wv & 3) * 64;

  const int sr = wv * 16 + (lane >> 2);
  const int sc = ((lane & 3) * 8) ^ (((sr >> 1) & 3) << 3);
  const int srg = m0 + sr;
  const unsigned short* abf =
      A + (size_t)(srg & 63) * 262144 + (srg >> 6) * 64 + sc;  // head-blocked
  const unsigned short* b0p = W + (size_t)(n0 + sr) * K + sc;
  const unsigned short* b1p = b0p + (size_t)128 * K;
  const int wl = wv * 512;

  const int x = ((l15 >> 1) & 3) << 3;
  const int aoff = (wmL + l15) * 32 + ((kg * 8) ^ x);
  const int boff = (wnL + l15) * 32 + ((kg * 8) ^ x);

  bf16x8 af[2][8], bfr[2][4];  // frag double buffers
  f32x4 acc[8][4];
#pragma unroll
  for (int i = 0; i < 8; ++i)
#pragma unroll
    for (int j = 0; j < 4; ++j) acc[i][j] = (f32x4){0.f, 0.f, 0.f, 0.f};

  OP_STAGE(0, 0); OP_STAGE(1, 1); OP_STAGE(2, 2);
  STEP_WAIT("vmcnt(4)")  // completes AB(0),AB(1); AB(2) in flight
  OP_PF(0, 0);

#pragma unroll 1
  for (int sb = 0; sb < 28; sb += 4) {
    OP_STEP(sb + 0, 0, 0, 1, 1);
    STEP_WAIT("vmcnt(4)")
    OP_STEP(sb + 1, 1, 1, 1, 1);
    STEP_WAIT("vmcnt(4)")
    OP_STEP(sb + 2, 0, 2, 1, 1);
    STEP_WAIT("vmcnt(4)")
    OP_STEP(sb + 3, 1, 3, 1, 1);
    STEP_WAIT("vmcnt(4)")
  }
  OP_STEP(28, 0, 0, 1, 1);   // stages AB(31)
  STEP_WAIT("vmcnt(4)")      // forces AB(30); AB(31) in flight
  OP_STEP(29, 1, 1, 0, 1);
  STEP_WAIT("vmcnt(0)")      // AB(31) complete before step-30 prefetch
  OP_STEP(30, 0, 2, 0, 1);
  STEP_WAIT("vmcnt(0)")
  OP_STEP(31, 1, 3, 0, 0);

#pragma unroll
  for (int mi = 0; mi < 8; ++mi) {
#pragma unroll
    for (int ni = 0; ni < 4; ++ni) {
      int col = n0 + wnL + ni * 16 + l15;
      float bcol = bias[col];
#pragma unroll
      for (int r = 0; r < 4; ++r) {
        int row = m0 + wmL + mi * 16 + kg * 4 + r;
        Cv[(size_t)row * N + col] = acc[mi][ni][r] + bcol;
      }
    }
  }
}

// ---------------------------------------------------------------------------
// MFMA attention per (b,h) — EXACT R4-proven kernel.
// ---------------------------------------------------------------------------
__global__ __launch_bounds__(512) void attn_kernel(
    const unsigned short* __restrict__ qb, const unsigned short* __restrict__ kb,
    const unsigned short* __restrict__ vb, const float* __restrict__ prefix,
    const float* __restrict__ bw, const float* __restrict__ g1,
    unsigned short* __restrict__ comb) {
  const int b = blockIdx.x, h = blockIdx.y;
  __shared__ __attribute__((aligned(16))) unsigned short Kl[256][64];
  __shared__ __attribute__((aligned(16))) unsigned short Vt[64 * 256];
  __shared__ __attribute__((aligned(16))) unsigned short PKl[16][64];
  __shared__ __attribute__((aligned(16))) unsigned short PVt[64][32];
  __shared__ __attribute__((aligned(16))) unsigned short Plds[8][16][40];
  unsigned short* Cb = &Kl[0][0];
  const int tid = threadIdx.x;
  const int wv = tid >> 6, lane = tid & 63;
  const size_t slab = (size_t)(b * NH + h) * 16384;

#pragma unroll
  for (int it = 0; it < 4; ++it) {
    int cid = tid + it * 512;
    int j = cid >> 3, c = cid & 7;
    gl_lds16(kb + slab + (size_t)j * 64 + ((c ^ (j & 7)) << 3),
             &Kl[0][0] + (size_t)(it * 512 + wv * 64) * 8);
    ushort8 vv = *(const ushort8*)(vb + slab + (size_t)j * 64 + (c << 3));
#pragma unroll
    for (int i = 0; i < 8; ++i) {
      int gran = (j >> 3) ^ i ^ c;
      Vt[(c * 8 + i) * 256 + gran * 8 + (j & 7)] = vv[i];
    }
  }
  if (tid < 256) {
    int arr = tid >> 7, cid = tid & 127;
    int sp = cid >> 3, c = cid & 7;
    const float* src = prefix + ((size_t)(b * 2 + arr) * PP + sp) * EMB + h * HD + c * 8;
    float4v v0 = *(const float4v*)src;
    float4v v1 = *(const float4v*)(src + 4);
    if (arr == 0) {
      ushort8 o = {f2b(v0[0]), f2b(v0[1]), f2b(v0[2]), f2b(v0[3]),
                   f2b(v1[0]), f2b(v1[1]), f2b(v1[2]), f2b(v1[3])};
      *(ushort8*)&PKl[sp][((c ^ (sp & 7)) << 3)] = o;
    } else {
#pragma unroll
      for (int i = 0; i < 8; ++i)
        PVt[c * 8 + i][sp] = f2b(i < 4 ? v0[i] : v1[i - 4]);
    }
  } else if (tid < 384) {
    int cid = tid - 256;
    *(ushort8*)&PVt[cid >> 1][16 + (cid & 1) * 8] = (ushort8){0, 0, 0, 0, 0, 0, 0, 0};
  }
  __syncthreads();

  const int l15 = lane & 15, g = lane >> 4;
  const int swl = l15 & 7;
  const float bwb = bw[b];
  unsigned short(&Pw)[16][40] = Plds[wv];

  const int t0 = wv * 32 + l15;
  const size_t qbase = slab + (size_t)t0 * 64;
  bf16x8 qf[2][2];
  qf[0][0] = *(const bf16x8*)(qb + qbase + g * 8);
  qf[0][1] = *(const bf16x8*)(qb + qbase + 32 + g * 8);
  qf[1][0] = *(const bf16x8*)(qb + qbase + 1024 + g * 8);
  qf[1][1] = *(const bf16x8*)(qb + qbase + 1024 + 32 + g * 8);

  f32x4 O[2][4];
#pragma unroll
  for (int st = 0; st < 2; ++st)
#pragma unroll
    for (int dt = 0; dt < 4; ++dt) O[st][dt] = (f32x4){0.f, 0.f, 0.f, 0.f};
  float m[2] = {-3.0e38f, -3.0e38f}, l[2] = {0.f, 0.f};

#pragma unroll
  for (int ch = 0; ch < 8; ++ch) {
    const int rA = ch * 32 + l15, rB = rA + 16;
    bf16x8 ka0 = *(const bf16x8*)&Kl[rA][((g ^ swl) << 3)];
    bf16x8 ka1 = *(const bf16x8*)&Kl[rA][(((4 + g) ^ swl) << 3)];
    bf16x8 kb0 = *(const bf16x8*)&Kl[rB][((g ^ swl) << 3)];
    bf16x8 kb1 = *(const bf16x8*)&Kl[rB][(((4 + g) ^ swl) << 3)];
    f32x4 s[2][2];
#pragma unroll
    for (int st = 0; st < 2; ++st) {
      s[st][0] = (f32x4){0.f, 0.f, 0.f, 0.f};
      s[st][1] = (f32x4){0.f, 0.f, 0.f, 0.f};
      s[st][0] = mfma16(ka0, qf[st][0], s[st][0]);
      s[st][0] = mfma16(ka1, qf[st][1], s[st][0]);
      s[st][1] = mfma16(kb0, qf[st][0], s[st][1]);
      s[st][1] = mfma16(kb1, qf[st][1], s[st][1]);
    }
    bf16x8 pf[2];
#pragma unroll
    for (int st = 0; st < 2; ++st) {
      f32x4 sa = s[st][0], sb = s[st][1];
      float mx = fmaxf(fmaxf(fmaxf(sa[0], sa[1]), fmaxf(sa[2], sa[3])),
                       fmaxf(fmaxf(sb[0], sb[1]), fmaxf(sb[2], sb[3])));
      mx = fmaxf(mx, __shfl_xor(mx, 16));
      mx = fmaxf(mx, __shfl_xor(mx, 32));
      if (__ballot(mx > m[st] + 8.0f) != 0ull) {
        float mn = fmaxf(m[st], mx);
        float f = __expf(m[st] - mn);
        m[st] = mn;
        l[st] *= f;
#pragma unroll
        for (int dt = 0; dt < 4; ++dt)
#pragma unroll
          for (int r = 0; r < 4; ++r) O[st][dt][r] *= f;
      }
      float pA[4], pB[4];
#pragma unroll
      for (int r = 0; r < 4; ++r) {
        pA[r] = __expf(sa[r] - m[st]);
        pB[r] = __expf(sb[r] - m[st]);
      }
      uint2v wa = {pack2(pA[0], pA[1]), pack2(pA[2], pA[3])};
      uint2v wb2 = {pack2(pB[0], pB[1]), pack2(pB[2], pB[3])};
      *(uint2v*)&Pw[l15][g * 4] = wa;
      *(uint2v*)&Pw[l15][16 + g * 4] = wb2;
      float sloc = b2f((unsigned short)(wa[0] & 0xffff)) + b2f((unsigned short)(wa[0] >> 16)) +
                   b2f((unsigned short)(wa[1] & 0xffff)) + b2f((unsigned short)(wa[1] >> 16)) +
                   b2f((unsigned short)(wb2[0] & 0xffff)) + b2f((unsigned short)(wb2[0] >> 16)) +
                   b2f((unsigned short)(wb2[1] & 0xffff)) + b2f((unsigned short)(wb2[1] >> 16));
      l[st] += sloc;
      pf[st] = *(const bf16x8*)&Pw[l15][g * 8];
    }
#pragma unroll
    for (int dt = 0; dt < 4; ++dt) {
      const int drow = dt * 16 + l15;
      const int gran = (ch * 4 + g) ^ (drow & 7) ^ (drow >> 3);
      bf16x8 vf = *(const bf16x8*)&Vt[drow * 256 + gran * 8];
      O[0][dt] = mfma16(vf, pf[0], O[0][dt]);
      O[1][dt] = mfma16(vf, pf[1], O[1][dt]);
    }
  }

#pragma unroll
  for (int st = 0; st < 2; ++st) {
    float lf = l[st];
    lf += __shfl_xor(lf, 16);
    lf += __shfl_xor(lf, 32);
    float inv = 1.0f / lf;
#pragma unroll
    for (int dt = 0; dt < 4; ++dt)
#pragma unroll
      for (int r = 0; r < 4; ++r) O[st][dt][r] *= inv;
  }

  {
    bf16x8 pk0 = *(const bf16x8*)&PKl[l15][((g ^ swl) << 3)];
    bf16x8 pk1 = *(const bf16x8*)&PKl[l15][(((4 + g) ^ swl) << 3)];
    bf16x8 ppf[2];
#pragma unroll
    for (int st = 0; st < 2; ++st) {
      f32x4 sp4 = (f32x4){0.f, 0.f, 0.f, 0.f};
      sp4 = mfma16(pk0, qf[st][0], sp4);
      sp4 = mfma16(pk1, qf[st][1], sp4);
      float pm = fmaxf(fmaxf(sp4[0], sp4[1]), fmaxf(sp4[2], sp4[3]));
      pm = fmaxf(pm, __shfl_xor(pm, 16));
      pm = fmaxf(pm, __shfl_xor(pm, 32));
      float pe[4], pl = 0.f;
#pragma unroll
      for (int r = 0; r < 4; ++r) {
        pe[r] = __expf(sp4[r] - pm);
        pl += pe[r];
      }
      pl += __shfl_xor(pl, 16);
      pl += __shfl_xor(pl, 32);
      float cpre = g1[(t0 + 16 * st) >> 2] * bwb / pl;
#pragma unroll
      for (int r = 0; r < 4; ++r) pe[r] *= cpre;
      *(uint2v*)&Pw[l15][g * 4] = (uint2v){pack2(pe[0], pe[1]), pack2(pe[2], pe[3])};
      *(uint2v*)&Pw[l15][16 + g * 4] = (uint2v){0u, 0u};
      ppf[st] = *(const bf16x8*)&Pw[l15][g * 8];
    }
#pragma unroll
    for (int dt = 0; dt < 4; ++dt) {
      bf16x8 pvf = *(const bf16x8*)&PVt[dt * 16 + l15][g * 8];
      O[0][dt] = mfma16(pvf, ppf[0], O[0][dt]);
      O[1][dt] = mfma16(pvf, ppf[1], O[1][dt]);
    }
  }

  __syncthreads();
#pragma unroll
  for (int st = 0; st < 2; ++st) {
    int t = wv * 32 + st * 16 + l15;
#pragma unroll
    for (int dt = 0; dt < 4; ++dt) {
#pragma unroll
      for (int u = 0; u < 2; ++u) {
        unsigned int pw = pack2(O[st][dt][2 * u], O[st][dt][2 * u + 1]);
        int d = dt * 16 + g * 4 + 2 * u;
        *(unsigned int*)&Cb[t * 64 + (((d >> 3) ^ (t & 7)) << 3) + (d & 7)] = pw;
      }
    }
  }
  __syncthreads();
#pragma unroll
  for (int it = 0; it < 4; ++it) {
    int cid = tid + it * 512;
    int j = cid >> 3, c = cid & 7;
    ushort8 row = *(const ushort8*)&Cb[j * 64 + ((c ^ (j & 7)) << 3)];
    *(ushort8*)(comb + slab + (size_t)j * 64 + (c << 3)) = row;
  }
}

// ---------------------------------------------------------------------------
extern "C" void kernel_launch(void* const* d_in, const int* in_sizes, int n_in,
                              void* d_out, int out_size, void* d_ws, size_t ws_size,
                              hipStream_t stream) {
  const float* query = (const float*)d_in[1];
  const float* key = (const float*)d_in[2];
  const float* value = (const float*)d_in[3];
  const float* prefix = (const float*)d_in[4];
  const float* bw = (const float*)d_in[5];
  const float* feat = (const float*)d_in[6];
  const float* noise = (const float*)d_in[7];
  const float* ipw = (const float*)d_in[8];
  const float* ipb = (const float*)d_in[9];
  const float* outw = (const float*)d_in[10];
  const float* outb = (const float*)d_in[11];
  const float* gw = (const float*)d_in[12];
  const float* gb = (const float*)d_in[13];
  float* out = (float*)d_out;

  char* ws = (char*)d_ws;
  const size_t MATB = (size_t)16384 * 1024;
  unsigned short* qb = (unsigned short*)ws;
  unsigned short* kb = qb + MATB;
  unsigned short* vb = kb + MATB;
  unsigned short* cb = vb + MATB;            // attn output (head-blocked)
  unsigned short* wip = cb + MATB;           // bf16 in_proj_w [3072,1024]
  unsigned short* wo = wip + (size_t)3072 * 1024;  // bf16 out_w [1024,1024]
  float* g1 = (float*)(wo + (size_t)1024 * 1024);

  gate_kernel<<<64, 64, 0, stream>>>(feat, gw, gb, noise, g1);

  cast_bf16_kernel<<<1536, 256, 0, stream>>>(ipw, wip, 3072 * 1024 / 8);
  cast_bf16_kernel<<<512, 256, 0, stream>>>(outw, wo, 1024 * 1024 / 8);

  // projections: f32 A direct, frag-prefetch pipeline
  proj_kernel<1><<<256, 512, 0, stream>>>(query, wip, ipb, qb);
  proj_kernel<0><<<256, 512, 0, stream>>>(key, wip + (size_t)1024 * 1024, ipb + 1024, kb);
  proj_kernel<0><<<256, 512, 0, stream>>>(value, wip + (size_t)2048 * 1024, ipb + 2048, vb);

  attn_kernel<<<dim3(64, 16), 512, 0, stream>>>(qb, kb, vb, prefix, bw, g1, cb);

  outproj_kernel<<<256, 512, 0, stream>>>(cb, wo, outb, out);
}

// Round 16
// 276.513 us; speedup vs baseline: 1.0742x; 1.0742x over previous
//
#include <hip/hip_runtime.h>

typedef __attribute__((ext_vector_type(8))) short bf16x8;
typedef __attribute__((ext_vector_type(4))) float f32x4;
typedef __attribute__((ext_vector_type(8))) unsigned short ushort8;
typedef __attribute__((ext_vector_type(4))) unsigned short ushort4v;
typedef __attribute__((ext_vector_type(4))) float float4v;
typedef __attribute__((ext_vector_type(2))) unsigned int uint2v;

#define TGT 256
#define BSZ 64
#define EMB 1024
#define NH 16
#define HD 64
#define PP 16

__device__ __forceinline__ float b2f(unsigned short u) {
  return __builtin_bit_cast(float, ((unsigned int)u) << 16);
}
__device__ __forceinline__ unsigned short f2b(float f) {
  unsigned int u = __builtin_bit_cast(unsigned int, f);
  u += 0x7fffu + ((u >> 16) & 1u);  // RNE; no NaNs in this workload
  return (unsigned short)(u >> 16);
}
__device__ __forceinline__ unsigned int pack2(float lo, float hi) {
  return (unsigned int)f2b(lo) | ((unsigned int)f2b(hi) << 16);
}
__device__ __forceinline__ f32x4 mfma16(bf16x8 a, bf16x8 b, f32x4 c) {
  return __builtin_amdgcn_mfma_f32_16x16x32_bf16(a, b, c, 0, 0, 0);
}
// async global->LDS, 16B per lane; LDS dest is wave-uniform base + lane*16
__device__ __forceinline__ void gl_lds16(const unsigned short* g, unsigned short* l) {
  __builtin_amdgcn_global_load_lds(
      (const __attribute__((address_space(1))) unsigned int*)g,
      (__attribute__((address_space(3))) unsigned int*)l, 16, 0, 0);
}

// ---------------------------------------------------------------------------
// Gate: g1[b] = softmax((feat[b]@gw.T + gb + noise[b]) / 3)[1]
// ---------------------------------------------------------------------------
__global__ __launch_bounds__(64) void gate_kernel(
    const float* __restrict__ feat, const float* __restrict__ gw,
    const float* __restrict__ gb, const float* __restrict__ noise,
    float* __restrict__ g1) {
  const int b = blockIdx.x, lane = threadIdx.x;
  float a0 = 0.f, a1 = 0.f;
  for (int i = lane; i < 512; i += 64) {
    float f = feat[b * 512 + i];
    a0 += f * gw[i];
    a1 += f * gw[512 + i];
  }
#pragma unroll
  for (int off = 32; off >= 1; off >>= 1) {
    a0 += __shfl_xor(a0, off);
    a1 += __shfl_xor(a1, off);
  }
  if (lane == 0) {
    float l0 = (a0 + gb[0] + noise[b * 2 + 0]) * (1.0f / 3.0f);
    float l1 = (a1 + gb[1] + noise[b * 2 + 1]) * (1.0f / 3.0f);
    float mm = fmaxf(l0, l1);
    float e0 = __expf(l0 - mm), e1 = __expf(l1 - mm);
    g1[b] = e1 / (e0 + e1);
  }
}

// ---------------------------------------------------------------------------
// f32 -> bf16 cast, 8 elems/thread, grid-stride (R4-proven, ~16us / 96MB)
// ---------------------------------------------------------------------------
__global__ __launch_bounds__(256) void cast_bf16_kernel(
    const float* __restrict__ in, unsigned short* __restrict__ out, int n8) {
  int i = blockIdx.x * blockDim.x + threadIdx.x;
  const int stride = gridDim.x * blockDim.x;
  for (; i < n8; i += stride) {
    const float4v* p = (const float4v*)(in + (size_t)i * 8);
    float4v v0 = p[0], v1 = p[1];
    ushort8 o = {f2b(v0[0]), f2b(v0[1]), f2b(v0[2]), f2b(v0[3]),
                 f2b(v1[0]), f2b(v1[1]), f2b(v1[2]), f2b(v1[3])};
    *(ushort8*)(out + (size_t)i * 8) = o;
  }
}

#define STEP_WAIT(cntstr)                                \
  asm volatile("s_waitcnt " cntstr ::: "memory");        \
  __builtin_amdgcn_sched_barrier(0);                     \
  __builtin_amdgcn_s_barrier();

// ---------------------------------------------------------------------------
// Single-barrier bf16 GEMM (R14-PASSED structure, the fast one: bf16-A
// outproj residual ~18us): C[16384,1024] = A_bf16 @ W_bf16^T + bias.
// 256x256 tile, 8 waves (2Mx4N, each 128x64), BK=32, 32 K-steps.
// Per step: {read 12 frags from slot s&3 | stage AB(s+3) via gl_lds |
// setprio MFMA 32 | vmcnt-backstop + barrier}. AB(s+3) writes slot
// (s-1)&3 whose readers all passed the previous barrier (ds_reads complete
// before their consuming MFMAs, which precede the barrier) -- R14-audited.
// Steady vmcnt(8) completes AB(s+1) one step before its frags are read.
// XCD-chunked block swizzle. A_BLOCKED selects head-blocked A layout
// [(b*16+h)][t][d]; OUT_F32=0 stores C head-blocked bf16 (+QSCALE=0.125
// for q); OUT_F32=1 stores row-major f32.
// ---------------------------------------------------------------------------
#define SB_AOFF(s) (A_BLOCKED ? (((s) >> 1) * 16384 + ((s)&1) * 32) : (s)*32)
#define SB_STAGE(s)                                      \
  {                                                      \
    const unsigned short* _ap = abf + SB_AOFF(s);        \
    unsigned short* da = &As[(s) & 3][wl];               \
    gl_lds16(_ap, da);                                   \
    gl_lds16(_ap + aD, da + 4096);                       \
    int k0s = (s) * 32;                                  \
    unsigned short* db = &Bs[(s) & 3][wl];               \
    gl_lds16(b0p + k0s, db);                             \
    gl_lds16(b1p + k0s, db + 4096);                      \
  }
#define SB_STEP(s, DO_STAGE)                                          \
  {                                                                   \
    const unsigned short* Ab = &As[(s) & 3][0];                       \
    const unsigned short* Bb = &Bs[(s) & 3][0];                       \
    bf16x8 af[8], bfr[4];                                             \
    _Pragma("unroll") for (int mi = 0; mi < 8; ++mi)                  \
        af[mi] = *(const bf16x8*)&Ab[aoff + mi * 512];                \
    _Pragma("unroll") for (int ni = 0; ni < 4; ++ni)                  \
        bfr[ni] = *(const bf16x8*)&Bb[boff + ni * 512];               \
    if (DO_STAGE) SB_STAGE((s) + 3);                                  \
    __builtin_amdgcn_s_setprio(1);                                    \
    _Pragma("unroll") for (int mi = 0; mi < 8; ++mi)                  \
      _Pragma("unroll") for (int ni = 0; ni < 4; ++ni)                \
        acc[mi][ni] = mfma16(af[mi], bfr[ni], acc[mi][ni]);           \
    __builtin_amdgcn_s_setprio(0);                                    \
  }

template <int OUT_F32, int QSCALE, int A_BLOCKED>
__global__ __launch_bounds__(512, 2) void gemm_sb_kernel(
    const unsigned short* __restrict__ A, const unsigned short* __restrict__ W,
    const float* __restrict__ bias, void* __restrict__ Cv) {
  constexpr int K = 1024, N = 1024;
  __shared__ __attribute__((aligned(16))) unsigned short As[4][8192];  // 64 KB
  __shared__ __attribute__((aligned(16))) unsigned short Bs[4][8192];  // 64 KB
  const int tid = threadIdx.x;
  const int wv = tid >> 6, lane = tid & 63;
  const int l15 = lane & 15, kg = lane >> 4;
  const int bid = blockIdx.x;
  const int cpx = gridDim.x >> 3;
  const int wg = (bid & 7) * cpx + (bid >> 3);
  const int m0 = (wg >> 2) * 256, n0 = (wg & 3) * 256;
  const int wmL = (wv >> 2) * 128, wnL = (wv & 3) * 64;

  const int sr = wv * 16 + (lane >> 2);                      // row in 128-half
  const int sc = ((lane & 3) * 8) ^ (((sr >> 1) & 3) << 3);  // pre-swizzled col
  const int srg = m0 + sr;
  const unsigned short* abf;
  if constexpr (A_BLOCKED)
    abf = A + (size_t)(srg & 63) * 262144 + (srg >> 6) * 64 + sc;
  else
    abf = A + (size_t)srg * K + sc;
  const int aD = A_BLOCKED ? 128 : 128 * K;  // +128 logical rows
  const unsigned short* b0p = W + (size_t)(n0 + sr) * K + sc;
  const unsigned short* b1p = b0p + (size_t)128 * K;
  const int wl = wv * 512;

  const int x = ((l15 >> 1) & 3) << 3;
  const int aoff = (wmL + l15) * 32 + ((kg * 8) ^ x);
  const int boff = (wnL + l15) * 32 + ((kg * 8) ^ x);

  f32x4 acc[8][4];
#pragma unroll
  for (int i = 0; i < 8; ++i)
#pragma unroll
    for (int j = 0; j < 4; ++j) acc[i][j] = (f32x4){0.f, 0.f, 0.f, 0.f};

  SB_STAGE(0); SB_STAGE(1); SB_STAGE(2);
  STEP_WAIT("vmcnt(8)")  // completes AB(0)

  for (int s = 0; s < 29; ++s) {
    SB_STEP(s, 1);
    STEP_WAIT("vmcnt(8)")  // completes AB(s+1)
  }
  SB_STEP(29, 0);
  STEP_WAIT("vmcnt(4)")    // completes AB(30)
  SB_STEP(30, 0);
  STEP_WAIT("vmcnt(0)")    // completes AB(31)
  SB_STEP(31, 0);

#pragma unroll
  for (int mi = 0; mi < 8; ++mi) {
#pragma unroll
    for (int ni = 0; ni < 4; ++ni) {
      int col = n0 + wnL + ni * 16 + l15;
      float bcol = bias[col];
#pragma unroll
      for (int r = 0; r < 4; ++r) {
        int row = m0 + wmL + mi * 16 + kg * 4 + r;
        float v = acc[mi][ni][r] + bcol;
        if constexpr (QSCALE) v *= 0.125f;
        if constexpr (OUT_F32) {
          ((float*)Cv)[(size_t)row * N + col] = v;
        } else {
          // head-blocked store: [(b*16+h)][t][d]
          int t = row >> 6, bb = row & 63, hh = col >> 6, dd = col & 63;
          ((unsigned short*)Cv)[(size_t)((bb * 16 + hh) * 256 + t) * 64 + dd] = f2b(v);
        }
      }
    }
  }
}

// ---------------------------------------------------------------------------
// MFMA attention per (b,h) — EXACT R4-proven kernel.
// q/k/v/comb HEAD-BLOCKED [(b*16+h)][t][d]; 8 waves x 32 t-rows,
// strip-merged; natural-log softmax via __expf; pack2/f2b packing;
// T13 defer-rescale; V^T gran swizzle.
// combined = attn + g1[t>>2]*bw[b]*attn_pre (uses g0+g1==1).
// Q pre-scaled by 0.125 in the q-projection.
// ---------------------------------------------------------------------------
__global__ __launch_bounds__(512) void attn_kernel(
    const unsigned short* __restrict__ qb, const unsigned short* __restrict__ kb,
    const unsigned short* __restrict__ vb, const float* __restrict__ prefix,
    const float* __restrict__ bw, const float* __restrict__ g1,
    unsigned short* __restrict__ comb) {
  const int b = blockIdx.x, h = blockIdx.y;
  __shared__ __attribute__((aligned(16))) unsigned short Kl[256][64];
  __shared__ __attribute__((aligned(16))) unsigned short Vt[64 * 256];
  __shared__ __attribute__((aligned(16))) unsigned short PKl[16][64];
  __shared__ __attribute__((aligned(16))) unsigned short PVt[64][32];
  __shared__ __attribute__((aligned(16))) unsigned short Plds[8][16][40];
  unsigned short* Cb = &Kl[0][0];
  const int tid = threadIdx.x;
  const int wv = tid >> 6, lane = tid & 63;
  const size_t slab = (size_t)(b * NH + h) * 16384;

#pragma unroll
  for (int it = 0; it < 4; ++it) {
    int cid = tid + it * 512;
    int j = cid >> 3, c = cid & 7;
    gl_lds16(kb + slab + (size_t)j * 64 + ((c ^ (j & 7)) << 3),
             &Kl[0][0] + (size_t)(it * 512 + wv * 64) * 8);
    ushort8 vv = *(const ushort8*)(vb + slab + (size_t)j * 64 + (c << 3));
#pragma unroll
    for (int i = 0; i < 8; ++i) {
      int gran = (j >> 3) ^ i ^ c;
      Vt[(c * 8 + i) * 256 + gran * 8 + (j & 7)] = vv[i];
    }
  }
  if (tid < 256) {
    int arr = tid >> 7, cid = tid & 127;
    int sp = cid >> 3, c = cid & 7;
    const float* src = prefix + ((size_t)(b * 2 + arr) * PP + sp) * EMB + h * HD + c * 8;
    float4v v0 = *(const float4v*)src;
    float4v v1 = *(const float4v*)(src + 4);
    if (arr == 0) {
      ushort8 o = {f2b(v0[0]), f2b(v0[1]), f2b(v0[2]), f2b(v0[3]),
                   f2b(v1[0]), f2b(v1[1]), f2b(v1[2]), f2b(v1[3])};
      *(ushort8*)&PKl[sp][((c ^ (sp & 7)) << 3)] = o;
    } else {
#pragma unroll
      for (int i = 0; i < 8; ++i)
        PVt[c * 8 + i][sp] = f2b(i < 4 ? v0[i] : v1[i - 4]);
    }
  } else if (tid < 384) {
    int cid = tid - 256;
    *(ushort8*)&PVt[cid >> 1][16 + (cid & 1) * 8] = (ushort8){0, 0, 0, 0, 0, 0, 0, 0};
  }
  __syncthreads();

  const int l15 = lane & 15, g = lane >> 4;
  const int swl = l15 & 7;
  const float bwb = bw[b];
  unsigned short(&Pw)[16][40] = Plds[wv];

  const int t0 = wv * 32 + l15;
  const size_t qbase = slab + (size_t)t0 * 64;
  bf16x8 qf[2][2];
  qf[0][0] = *(const bf16x8*)(qb + qbase + g * 8);
  qf[0][1] = *(const bf16x8*)(qb + qbase + 32 + g * 8);
  qf[1][0] = *(const bf16x8*)(qb + qbase + 1024 + g * 8);
  qf[1][1] = *(const bf16x8*)(qb + qbase + 1024 + 32 + g * 8);

  f32x4 O[2][4];
#pragma unroll
  for (int st = 0; st < 2; ++st)
#pragma unroll
    for (int dt = 0; dt < 4; ++dt) O[st][dt] = (f32x4){0.f, 0.f, 0.f, 0.f};
  float m[2] = {-3.0e38f, -3.0e38f}, l[2] = {0.f, 0.f};

#pragma unroll
  for (int ch = 0; ch < 8; ++ch) {
    const int rA = ch * 32 + l15, rB = rA + 16;
    bf16x8 ka0 = *(const bf16x8*)&Kl[rA][((g ^ swl) << 3)];
    bf16x8 ka1 = *(const bf16x8*)&Kl[rA][(((4 + g) ^ swl) << 3)];
    bf16x8 kb0 = *(const bf16x8*)&Kl[rB][((g ^ swl) << 3)];
    bf16x8 kb1 = *(const bf16x8*)&Kl[rB][(((4 + g) ^ swl) << 3)];
    f32x4 s[2][2];
#pragma unroll
    for (int st = 0; st < 2; ++st) {
      s[st][0] = (f32x4){0.f, 0.f, 0.f, 0.f};
      s[st][1] = (f32x4){0.f, 0.f, 0.f, 0.f};
      s[st][0] = mfma16(ka0, qf[st][0], s[st][0]);
      s[st][0] = mfma16(ka1, qf[st][1], s[st][0]);
      s[st][1] = mfma16(kb0, qf[st][0], s[st][1]);
      s[st][1] = mfma16(kb1, qf[st][1], s[st][1]);
    }
    bf16x8 pf[2];
#pragma unroll
    for (int st = 0; st < 2; ++st) {
      f32x4 sa = s[st][0], sb = s[st][1];
      float mx = fmaxf(fmaxf(fmaxf(sa[0], sa[1]), fmaxf(sa[2], sa[3])),
                       fmaxf(fmaxf(sb[0], sb[1]), fmaxf(sb[2], sb[3])));
      mx = fmaxf(mx, __shfl_xor(mx, 16));
      mx = fmaxf(mx, __shfl_xor(mx, 32));
      if (__ballot(mx > m[st] + 8.0f) != 0ull) {
        float mn = fmaxf(m[st], mx);
        float f = __expf(m[st] - mn);
        m[st] = mn;
        l[st] *= f;
#pragma unroll
        for (int dt = 0; dt < 4; ++dt)
#pragma unroll
          for (int r = 0; r < 4; ++r) O[st][dt][r] *= f;
      }
      float pA[4], pB[4];
#pragma unroll
      for (int r = 0; r < 4; ++r) {
        pA[r] = __expf(sa[r] - m[st]);
        pB[r] = __expf(sb[r] - m[st]);
      }
      uint2v wa = {pack2(pA[0], pA[1]), pack2(pA[2], pA[3])};
      uint2v wb2 = {pack2(pB[0], pB[1]), pack2(pB[2], pB[3])};
      *(uint2v*)&Pw[l15][g * 4] = wa;
      *(uint2v*)&Pw[l15][16 + g * 4] = wb2;
      float sloc = b2f((unsigned short)(wa[0] & 0xffff)) + b2f((unsigned short)(wa[0] >> 16)) +
                   b2f((unsigned short)(wa[1] & 0xffff)) + b2f((unsigned short)(wa[1] >> 16)) +
                   b2f((unsigned short)(wb2[0] & 0xffff)) + b2f((unsigned short)(wb2[0] >> 16)) +
                   b2f((unsigned short)(wb2[1] & 0xffff)) + b2f((unsigned short)(wb2[1] >> 16));
      l[st] += sloc;
      pf[st] = *(const bf16x8*)&Pw[l15][g * 8];
    }
#pragma unroll
    for (int dt = 0; dt < 4; ++dt) {
      const int drow = dt * 16 + l15;
      const int gran = (ch * 4 + g) ^ (drow & 7) ^ (drow >> 3);
      bf16x8 vf = *(const bf16x8*)&Vt[drow * 256 + gran * 8];
      O[0][dt] = mfma16(vf, pf[0], O[0][dt]);
      O[1][dt] = mfma16(vf, pf[1], O[1][dt]);
    }
  }

#pragma unroll
  for (int st = 0; st < 2; ++st) {
    float lf = l[st];
    lf += __shfl_xor(lf, 16);
    lf += __shfl_xor(lf, 32);
    float inv = 1.0f / lf;
#pragma unroll
    for (int dt = 0; dt < 4; ++dt)
#pragma unroll
      for (int r = 0; r < 4; ++r) O[st][dt][r] *= inv;
  }

  {
    bf16x8 pk0 = *(const bf16x8*)&PKl[l15][((g ^ swl) << 3)];
    bf16x8 pk1 = *(const bf16x8*)&PKl[l15][(((4 + g) ^ swl) << 3)];
    bf16x8 ppf[2];
#pragma unroll
    for (int st = 0; st < 2; ++st) {
      f32x4 sp4 = (f32x4){0.f, 0.f, 0.f, 0.f};
      sp4 = mfma16(pk0, qf[st][0], sp4);
      sp4 = mfma16(pk1, qf[st][1], sp4);
      float pm = fmaxf(fmaxf(sp4[0], sp4[1]), fmaxf(sp4[2], sp4[3]));
      pm = fmaxf(pm, __shfl_xor(pm, 16));
      pm = fmaxf(pm, __shfl_xor(pm, 32));
      float pe[4], pl = 0.f;
#pragma unroll
      for (int r = 0; r < 4; ++r) {
        pe[r] = __expf(sp4[r] - pm);
        pl += pe[r];
      }
      pl += __shfl_xor(pl, 16);
      pl += __shfl_xor(pl, 32);
      float cpre = g1[(t0 + 16 * st) >> 2] * bwb / pl;
#pragma unroll
      for (int r = 0; r < 4; ++r) pe[r] *= cpre;
      *(uint2v*)&Pw[l15][g * 4] = (uint2v){pack2(pe[0], pe[1]), pack2(pe[2], pe[3])};
      *(uint2v*)&Pw[l15][16 + g * 4] = (uint2v){0u, 0u};
      ppf[st] = *(const bf16x8*)&Pw[l15][g * 8];
    }
#pragma unroll
    for (int dt = 0; dt < 4; ++dt) {
      bf16x8 pvf = *(const bf16x8*)&PVt[dt * 16 + l15][g * 8];
      O[0][dt] = mfma16(pvf, ppf[0], O[0][dt]);
      O[1][dt] = mfma16(pvf, ppf[1], O[1][dt]);
    }
  }

  __syncthreads();
#pragma unroll
  for (int st = 0; st < 2; ++st) {
    int t = wv * 32 + st * 16 + l15;
#pragma unroll
    for (int dt = 0; dt < 4; ++dt) {
#pragma unroll
      for (int u = 0; u < 2; ++u) {
        unsigned int pw = pack2(O[st][dt][2 * u], O[st][dt][2 * u + 1]);
        int d = dt * 16 + g * 4 + 2 * u;
        *(unsigned int*)&Cb[t * 64 + (((d >> 3) ^ (t & 7)) << 3) + (d & 7)] = pw;
      }
    }
  }
  __syncthreads();
#pragma unroll
  for (int it = 0; it < 4; ++it) {
    int cid = tid + it * 512;
    int j = cid >> 3, c = cid & 7;
    ushort8 row = *(const ushort8*)&Cb[j * 64 + ((c ^ (j & 7)) << 3)];
    *(ushort8*)(comb + slab + (size_t)j * 64 + (c << 3)) = row;
  }
}

// ---------------------------------------------------------------------------
extern "C" void kernel_launch(void* const* d_in, const int* in_sizes, int n_in,
                              void* d_out, int out_size, void* d_ws, size_t ws_size,
                              hipStream_t stream) {
  const float* query = (const float*)d_in[1];
  const float* key = (const float*)d_in[2];
  const float* value = (const float*)d_in[3];
  const float* prefix = (const float*)d_in[4];
  const float* bw = (const float*)d_in[5];
  const float* feat = (const float*)d_in[6];
  const float* noise = (const float*)d_in[7];
  const float* ipw = (const float*)d_in[8];
  const float* ipb = (const float*)d_in[9];
  const float* outw = (const float*)d_in[10];
  const float* outb = (const float*)d_in[11];
  const float* gw = (const float*)d_in[12];
  const float* gb = (const float*)d_in[13];
  float* out = (float*)d_out;

  char* ws = (char*)d_ws;
  const size_t MATB = (size_t)16384 * 1024;  // elements per [16384,1024] matrix
  unsigned short* qb = (unsigned short*)ws;
  unsigned short* kb = qb + MATB;
  unsigned short* vb = kb + MATB;
  unsigned short* cb = vb + MATB;            // attn output; also A-cast scratch
  unsigned short* wip = cb + MATB;           // bf16 in_proj_w [3072,1024]
  unsigned short* wo = wip + (size_t)3072 * 1024;  // bf16 out_w [1024,1024]
  float* g1 = (float*)(wo + (size_t)1024 * 1024);

  gate_kernel<<<64, 64, 0, stream>>>(feat, gw, gb, noise, g1);

  // weight casts (16.8 MB total)
  cast_bf16_kernel<<<1536, 256, 0, stream>>>(ipw, wip, 3072 * 1024 / 8);
  cast_bf16_kernel<<<512, 256, 0, stream>>>(outw, wo, 1024 * 1024 / 8);

  const int N8 = (int)(MATB / 8);
  // q projection (cb used as bf16-A scratch before attn overwrites it)
  cast_bf16_kernel<<<2048, 256, 0, stream>>>(query, cb, N8);
  gemm_sb_kernel<0, 1, 0><<<256, 512, 0, stream>>>(cb, wip, ipb, qb);
  // k projection
  cast_bf16_kernel<<<2048, 256, 0, stream>>>(key, cb, N8);
  gemm_sb_kernel<0, 0, 0><<<256, 512, 0, stream>>>(cb, wip + (size_t)1024 * 1024, ipb + 1024, kb);
  // v projection
  cast_bf16_kernel<<<2048, 256, 0, stream>>>(value, cb, N8);
  gemm_sb_kernel<0, 0, 0><<<256, 512, 0, stream>>>(cb, wip + (size_t)2048 * 1024, ipb + 2048, vb);

  attn_kernel<<<dim3(64, 16), 512, 0, stream>>>(qb, kb, vb, prefix, bw, g1, cb);

  // out-projection reads head-blocked bf16 attn output
  gemm_sb_kernel<1, 0, 1><<<256, 512, 0, stream>>>(cb, wo, outb, out);
}

// Round 17
// 274.632 us; speedup vs baseline: 1.0815x; 1.0068x over previous
//
#include <hip/hip_runtime.h>

typedef __attribute__((ext_vector_type(8))) short bf16x8;
typedef __attribute__((ext_vector_type(4))) float f32x4;
typedef __attribute__((ext_vector_type(8))) unsigned short ushort8;
typedef __attribute__((ext_vector_type(4))) unsigned short ushort4v;
typedef __attribute__((ext_vector_type(4))) float float4v;
typedef __attribute__((ext_vector_type(2))) unsigned int uint2v;

#define TGT 256
#define BSZ 64
#define EMB 1024
#define NH 16
#define HD 64
#define PP 16

__device__ __forceinline__ float b2f(unsigned short u) {
  return __builtin_bit_cast(float, ((unsigned int)u) << 16);
}
__device__ __forceinline__ unsigned short f2b(float f) {
  unsigned int u = __builtin_bit_cast(unsigned int, f);
  u += 0x7fffu + ((u >> 16) & 1u);  // RNE; no NaNs in this workload
  return (unsigned short)(u >> 16);
}
__device__ __forceinline__ unsigned int pack2(float lo, float hi) {
  return (unsigned int)f2b(lo) | ((unsigned int)f2b(hi) << 16);
}
__device__ __forceinline__ f32x4 mfma16(bf16x8 a, bf16x8 b, f32x4 c) {
  return __builtin_amdgcn_mfma_f32_16x16x32_bf16(a, b, c, 0, 0, 0);
}
// async global->LDS, 16B per lane; LDS dest is wave-uniform base + lane*16
__device__ __forceinline__ void gl_lds16(const unsigned short* g, unsigned short* l) {
  __builtin_amdgcn_global_load_lds(
      (const __attribute__((address_space(1))) unsigned int*)g,
      (__attribute__((address_space(3))) unsigned int*)l, 16, 0, 0);
}

// ---------------------------------------------------------------------------
// Gate: g1[b] = softmax((feat[b]@gw.T + gb + noise[b]) / 3)[1]
// ---------------------------------------------------------------------------
__global__ __launch_bounds__(64) void gate_kernel(
    const float* __restrict__ feat, const float* __restrict__ gw,
    const float* __restrict__ gb, const float* __restrict__ noise,
    float* __restrict__ g1) {
  const int b = blockIdx.x, lane = threadIdx.x;
  float a0 = 0.f, a1 = 0.f;
  for (int i = lane; i < 512; i += 64) {
    float f = feat[b * 512 + i];
    a0 += f * gw[i];
    a1 += f * gw[512 + i];
  }
#pragma unroll
  for (int off = 32; off >= 1; off >>= 1) {
    a0 += __shfl_xor(a0, off);
    a1 += __shfl_xor(a1, off);
  }
  if (lane == 0) {
    float l0 = (a0 + gb[0] + noise[b * 2 + 0]) * (1.0f / 3.0f);
    float l1 = (a1 + gb[1] + noise[b * 2 + 1]) * (1.0f / 3.0f);
    float mm = fmaxf(l0, l1);
    float e0 = __expf(l0 - mm), e1 = __expf(l1 - mm);
    g1[b] = e1 / (e0 + e1);
  }
}

// ---------------------------------------------------------------------------
// f32 -> bf16 cast, 8 elems/thread, grid-stride (R4-proven, ~16us / 96MB)
// ---------------------------------------------------------------------------
__global__ __launch_bounds__(256) void cast_bf16_kernel(
    const float* __restrict__ in, unsigned short* __restrict__ out, int n8) {
  int i = blockIdx.x * blockDim.x + threadIdx.x;
  const int stride = gridDim.x * blockDim.x;
  for (; i < n8; i += stride) {
    const float4v* p = (const float4v*)(in + (size_t)i * 8);
    float4v v0 = p[0], v1 = p[1];
    ushort8 o = {f2b(v0[0]), f2b(v0[1]), f2b(v0[2]), f2b(v0[3]),
                 f2b(v1[0]), f2b(v1[1]), f2b(v1[2]), f2b(v1[3])};
    *(ushort8*)(out + (size_t)i * 8) = o;
  }
}

#define STEP_WAIT(cntstr)                                \
  asm volatile("s_waitcnt " cntstr ::: "memory");        \
  __builtin_amdgcn_sched_barrier(0);                     \
  __builtin_amdgcn_s_barrier();

// ---------------------------------------------------------------------------
// bf16 GEMM, R4/R11-PROVEN 4-barrier skeleton: C = A_bf16 @ W^T + bias.
// 256x256 tile, 8 waves, BK=32, lead-3 ring-4 gl_lds for A and B,
// counted vmcnt(8)/4/0, XCD-chunked swizzle, setprio.
//
// EPILOGUE (the R17 fix): head-blocked bf16 output (OUT_F32=0) was 128
// scattered 2B stores/thread (32B-fragment writes -> ~1M partial-line HBM
// transactions; measured 40-43us vs the 15us HBM floor of the coalesced-
// store outproj with the SAME K-loop). Now bounced through LDS per
// mi-chunk: waves deposit their 32x256 sub-tile (row pad +8 ushorts), then
// 512 threads store ushort8 chunks -- 8 threads cover one 128B-contiguous
// run (fixed (bb,hh,t), d 0..63). Same f2b(acc+bias) values, reordered ->
// bit-identical. OUT_F32=1 keeps the proven direct coalesced f32 store.
// A_BLOCKED: A in head-blocked layout [(b*16+h)][t][d].
// ---------------------------------------------------------------------------
#define AOFF(s) (A_BLOCKED ? (((s) >> 1) * 16384 + ((s)&1) * 32) : (s)*32)
#define STAGE_A(s)                                       \
  {                                                      \
    const unsigned short* _ap = abf + AOFF(s);           \
    unsigned short* d = &As[(s) & 3][wl];                \
    gl_lds16(_ap, d);                                    \
    gl_lds16(_ap + aD, d + 4096);                        \
  }
#define STAGE_B(s)                                       \
  {                                                      \
    int k0s = (s) * 32;                                  \
    unsigned short* d = &Bs[(s) & 3][wl];                \
    gl_lds16(b0p + k0s, d);                              \
    gl_lds16(b1p + k0s, d + 4096);                       \
  }
#define GEMM_STEP(s, DO_STAGE)                                        \
  {                                                                   \
    const unsigned short* Ab = &As[(s) & 3][0];                       \
    const unsigned short* Bb = &Bs[(s) & 3][0];                       \
    bf16x8 af[8], bfr[4];                                             \
    _Pragma("unroll") for (int mi = 0; mi < 8; ++mi)                  \
        af[mi] = *(const bf16x8*)&Ab[aoff + mi * 512];                \
    _Pragma("unroll") for (int ni = 0; ni < 2; ++ni)                  \
        bfr[ni] = *(const bf16x8*)&Bb[boff + ni * 512];               \
    if (DO_STAGE) STAGE_A((s) + 3);                                   \
    __builtin_amdgcn_s_barrier();                                     \
    __builtin_amdgcn_s_setprio(1);                                    \
    _Pragma("unroll") for (int mi = 0; mi < 8; ++mi) {                \
      acc[mi][0] = mfma16(af[mi], bfr[0], acc[mi][0]);                \
      acc[mi][1] = mfma16(af[mi], bfr[1], acc[mi][1]);                \
    }                                                                 \
    __builtin_amdgcn_s_setprio(0);                                    \
    __builtin_amdgcn_s_barrier();                                     \
    _Pragma("unroll") for (int ni = 2; ni < 4; ++ni)                  \
        bfr[ni] = *(const bf16x8*)&Bb[boff + ni * 512];               \
    if (DO_STAGE) STAGE_B((s) + 3);                                   \
    __builtin_amdgcn_s_barrier();                                     \
    __builtin_amdgcn_s_setprio(1);                                    \
    _Pragma("unroll") for (int mi = 0; mi < 8; ++mi) {                \
      acc[mi][2] = mfma16(af[mi], bfr[2], acc[mi][2]);                \
      acc[mi][3] = mfma16(af[mi], bfr[3], acc[mi][3]);                \
    }                                                                 \
    __builtin_amdgcn_s_setprio(0);                                    \
  }

template <int OUT_F32, int QSCALE, int A_BLOCKED>
__global__ __launch_bounds__(512, 2) void gemm4b_kernel(
    const unsigned short* __restrict__ A, const unsigned short* __restrict__ W,
    const float* __restrict__ bias, void* __restrict__ Cv) {
  constexpr int K = 1024, N = 1024;
  __shared__ __attribute__((aligned(16))) unsigned short As[4][8192];  // 64 KB
  __shared__ __attribute__((aligned(16))) unsigned short Bs[4][8192];  // 64 KB
  const int tid = threadIdx.x;
  const int wv = tid >> 6, lane = tid & 63;
  const int l15 = lane & 15, kg = lane >> 4;
  const int bid = blockIdx.x;
  const int cpx = gridDim.x >> 3;
  const int wg = (bid & 7) * cpx + (bid >> 3);
  const int m0 = (wg >> 2) * 256, n0 = (wg & 3) * 256;
  const int wmL = (wv >> 2) * 128, wnL = (wv & 3) * 64;

  const int sr = wv * 16 + (lane >> 2);                      // row in 128-half
  const int sc = ((lane & 3) * 8) ^ (((sr >> 1) & 3) << 3);  // pre-swizzled col
  const int srg = m0 + sr;
  const unsigned short* abf;
  if constexpr (A_BLOCKED)
    abf = A + (size_t)(srg & 63) * 262144 + (srg >> 6) * 64 + sc;
  else
    abf = A + (size_t)srg * K + sc;
  const int aD = A_BLOCKED ? 128 : 128 * K;  // +128 logical rows
  const unsigned short* b0p = W + (size_t)(n0 + sr) * K + sc;
  const unsigned short* b1p = b0p + (size_t)128 * K;
  const int wl = wv * 512;

  const int x = ((l15 >> 1) & 3) << 3;
  const int aoff = (wmL + l15) * 32 + ((kg * 8) ^ x);
  const int boff = (wnL + l15) * 32 + ((kg * 8) ^ x);

  f32x4 acc[8][4];
#pragma unroll
  for (int i = 0; i < 8; ++i)
#pragma unroll
    for (int j = 0; j < 4; ++j) acc[i][j] = (f32x4){0.f, 0.f, 0.f, 0.f};

  STAGE_A(0); STAGE_B(0); STAGE_A(1); STAGE_B(1); STAGE_A(2); STAGE_B(2);
  STEP_WAIT("vmcnt(8)")

  for (int s = 0; s < 29; ++s) {
    GEMM_STEP(s, 1);
    STEP_WAIT("vmcnt(8)")
  }
  GEMM_STEP(29, 0);
  STEP_WAIT("vmcnt(4)")
  GEMM_STEP(30, 0);
  STEP_WAIT("vmcnt(0)")
  GEMM_STEP(31, 0);

  if constexpr (OUT_F32) {
    // direct coalesced f32 store (R11/R13-proven, ~HBM floor)
#pragma unroll
    for (int mi = 0; mi < 8; ++mi) {
#pragma unroll
      for (int ni = 0; ni < 4; ++ni) {
        int col = n0 + wnL + ni * 16 + l15;
        float bcol = bias[col];
#pragma unroll
        for (int r = 0; r < 4; ++r) {
          int row = m0 + wmL + mi * 16 + kg * 4 + r;
          ((float*)Cv)[(size_t)row * N + col] = acc[mi][ni][r] + bcol;
        }
      }
    }
  } else {
    // LDS-bounce coalesced head-blocked bf16 store
    unsigned short* Bt = &As[0][0];  // 32 x (256+8) ushorts = 16.5 KB
    const int half = wv >> 2;
    float bcol[4];
#pragma unroll
    for (int ni = 0; ni < 4; ++ni) bcol[ni] = bias[n0 + wnL + ni * 16 + l15];
#pragma unroll
    for (int mi = 0; mi < 8; ++mi) {
      __syncthreads();  // prior reads of Bt (or of As in K-loop) done
#pragma unroll
      for (int ni = 0; ni < 4; ++ni) {
#pragma unroll
        for (int r = 0; r < 4; ++r) {
          float v = acc[mi][ni][r] + bcol[ni];
          if constexpr (QSCALE) v *= 0.125f;
          int rloc = half * 16 + kg * 4 + r;
          Bt[rloc * 264 + wnL + ni * 16 + l15] = f2b(v);
        }
      }
      __syncthreads();
      // cooperative store: 32 rows x 256 cols; 8 threads = one 128B run
#pragma unroll
      for (int it2 = 0; it2 < 2; ++it2) {
        int c2 = tid + it2 * 512;       // 0..1023
        int rloc = c2 >> 5;             // 0..31
        int cc = (c2 & 31) * 8;         // 0..248
        int grow = m0 + (rloc >> 4) * 128 + mi * 16 + (rloc & 15);
        int col = n0 + cc;
        int t = grow >> 6, bb = grow & 63, hh = col >> 6, dd = col & 63;
        ushort8 vv = *(const ushort8*)&Bt[rloc * 264 + cc];
        *(ushort8*)&((unsigned short*)Cv)[(size_t)((bb * 16 + hh) * 256 + t) * 64 + dd] = vv;
      }
    }
  }
}

// ---------------------------------------------------------------------------
// MFMA attention per (b,h) — EXACT R4-proven kernel.
// q/k/v/comb HEAD-BLOCKED [(b*16+h)][t][d]; 8 waves x 32 t-rows,
// strip-merged; natural-log softmax via __expf; pack2/f2b packing;
// T13 defer-rescale; V^T gran swizzle.
// combined = attn + g1[t>>2]*bw[b]*attn_pre (uses g0+g1==1).
// Q pre-scaled by 0.125 in the q-projection.
// ---------------------------------------------------------------------------
__global__ __launch_bounds__(512) void attn_kernel(
    const unsigned short* __restrict__ qb, const unsigned short* __restrict__ kb,
    const unsigned short* __restrict__ vb, const float* __restrict__ prefix,
    const float* __restrict__ bw, const float* __restrict__ g1,
    unsigned short* __restrict__ comb) {
  const int b = blockIdx.x, h = blockIdx.y;
  __shared__ __attribute__((aligned(16))) unsigned short Kl[256][64];
  __shared__ __attribute__((aligned(16))) unsigned short Vt[64 * 256];
  __shared__ __attribute__((aligned(16))) unsigned short PKl[16][64];
  __shared__ __attribute__((aligned(16))) unsigned short PVt[64][32];
  __shared__ __attribute__((aligned(16))) unsigned short Plds[8][16][40];
  unsigned short* Cb = &Kl[0][0];
  const int tid = threadIdx.x;
  const int wv = tid >> 6, lane = tid & 63;
  const size_t slab = (size_t)(b * NH + h) * 16384;

#pragma unroll
  for (int it = 0; it < 4; ++it) {
    int cid = tid + it * 512;
    int j = cid >> 3, c = cid & 7;
    gl_lds16(kb + slab + (size_t)j * 64 + ((c ^ (j & 7)) << 3),
             &Kl[0][0] + (size_t)(it * 512 + wv * 64) * 8);
    ushort8 vv = *(const ushort8*)(vb + slab + (size_t)j * 64 + (c << 3));
#pragma unroll
    for (int i = 0; i < 8; ++i) {
      int gran = (j >> 3) ^ i ^ c;
      Vt[(c * 8 + i) * 256 + gran * 8 + (j & 7)] = vv[i];
    }
  }
  if (tid < 256) {
    int arr = tid >> 7, cid = tid & 127;
    int sp = cid >> 3, c = cid & 7;
    const float* src = prefix + ((size_t)(b * 2 + arr) * PP + sp) * EMB + h * HD + c * 8;
    float4v v0 = *(const float4v*)src;
    float4v v1 = *(const float4v*)(src + 4);
    if (arr == 0) {
      ushort8 o = {f2b(v0[0]), f2b(v0[1]), f2b(v0[2]), f2b(v0[3]),
                   f2b(v1[0]), f2b(v1[1]), f2b(v1[2]), f2b(v1[3])};
      *(ushort8*)&PKl[sp][((c ^ (sp & 7)) << 3)] = o;
    } else {
#pragma unroll
      for (int i = 0; i < 8; ++i)
        PVt[c * 8 + i][sp] = f2b(i < 4 ? v0[i] : v1[i - 4]);
    }
  } else if (tid < 384) {
    int cid = tid - 256;
    *(ushort8*)&PVt[cid >> 1][16 + (cid & 1) * 8] = (ushort8){0, 0, 0, 0, 0, 0, 0, 0};
  }
  __syncthreads();

  const int l15 = lane & 15, g = lane >> 4;
  const int swl = l15 & 7;
  const float bwb = bw[b];
  unsigned short(&Pw)[16][40] = Plds[wv];

  const int t0 = wv * 32 + l15;
  const size_t qbase = slab + (size_t)t0 * 64;
  bf16x8 qf[2][2];
  qf[0][0] = *(const bf16x8*)(qb + qbase + g * 8);
  qf[0][1] = *(const bf16x8*)(qb + qbase + 32 + g * 8);
  qf[1][0] = *(const bf16x8*)(qb + qbase + 1024 + g * 8);
  qf[1][1] = *(const bf16x8*)(qb + qbase + 1024 + 32 + g * 8);

  f32x4 O[2][4];
#pragma unroll
  for (int st = 0; st < 2; ++st)
#pragma unroll
    for (int dt = 0; dt < 4; ++dt) O[st][dt] = (f32x4){0.f, 0.f, 0.f, 0.f};
  float m[2] = {-3.0e38f, -3.0e38f}, l[2] = {0.f, 0.f};

#pragma unroll
  for (int ch = 0; ch < 8; ++ch) {
    const int rA = ch * 32 + l15, rB = rA + 16;
    bf16x8 ka0 = *(const bf16x8*)&Kl[rA][((g ^ swl) << 3)];
    bf16x8 ka1 = *(const bf16x8*)&Kl[rA][(((4 + g) ^ swl) << 3)];
    bf16x8 kb0 = *(const bf16x8*)&Kl[rB][((g ^ swl) << 3)];
    bf16x8 kb1 = *(const bf16x8*)&Kl[rB][(((4 + g) ^ swl) << 3)];
    f32x4 s[2][2];
#pragma unroll
    for (int st = 0; st < 2; ++st) {
      s[st][0] = (f32x4){0.f, 0.f, 0.f, 0.f};
      s[st][1] = (f32x4){0.f, 0.f, 0.f, 0.f};
      s[st][0] = mfma16(ka0, qf[st][0], s[st][0]);
      s[st][0] = mfma16(ka1, qf[st][1], s[st][0]);
      s[st][1] = mfma16(kb0, qf[st][0], s[st][1]);
      s[st][1] = mfma16(kb1, qf[st][1], s[st][1]);
    }
    bf16x8 pf[2];
#pragma unroll
    for (int st = 0; st < 2; ++st) {
      f32x4 sa = s[st][0], sb = s[st][1];
      float mx = fmaxf(fmaxf(fmaxf(sa[0], sa[1]), fmaxf(sa[2], sa[3])),
                       fmaxf(fmaxf(sb[0], sb[1]), fmaxf(sb[2], sb[3])));
      mx = fmaxf(mx, __shfl_xor(mx, 16));
      mx = fmaxf(mx, __shfl_xor(mx, 32));
      if (__ballot(mx > m[st] + 8.0f) != 0ull) {
        float mn = fmaxf(m[st], mx);
        float f = __expf(m[st] - mn);
        m[st] = mn;
        l[st] *= f;
#pragma unroll
        for (int dt = 0; dt < 4; ++dt)
#pragma unroll
          for (int r = 0; r < 4; ++r) O[st][dt][r] *= f;
      }
      float pA[4], pB[4];
#pragma unroll
      for (int r = 0; r < 4; ++r) {
        pA[r] = __expf(sa[r] - m[st]);
        pB[r] = __expf(sb[r] - m[st]);
      }
      uint2v wa = {pack2(pA[0], pA[1]), pack2(pA[2], pA[3])};
      uint2v wb2 = {pack2(pB[0], pB[1]), pack2(pB[2], pB[3])};
      *(uint2v*)&Pw[l15][g * 4] = wa;
      *(uint2v*)&Pw[l15][16 + g * 4] = wb2;
      float sloc = b2f((unsigned short)(wa[0] & 0xffff)) + b2f((unsigned short)(wa[0] >> 16)) +
                   b2f((unsigned short)(wa[1] & 0xffff)) + b2f((unsigned short)(wa[1] >> 16)) +
                   b2f((unsigned short)(wb2[0] & 0xffff)) + b2f((unsigned short)(wb2[0] >> 16)) +
                   b2f((unsigned short)(wb2[1] & 0xffff)) + b2f((unsigned short)(wb2[1] >> 16));
      l[st] += sloc;
      pf[st] = *(const bf16x8*)&Pw[l15][g * 8];
    }
#pragma unroll
    for (int dt = 0; dt < 4; ++dt) {
      const int drow = dt * 16 + l15;
      const int gran = (ch * 4 + g) ^ (drow & 7) ^ (drow >> 3);
      bf16x8 vf = *(const bf16x8*)&Vt[drow * 256 + gran * 8];
      O[0][dt] = mfma16(vf, pf[0], O[0][dt]);
      O[1][dt] = mfma16(vf, pf[1], O[1][dt]);
    }
  }

#pragma unroll
  for (int st = 0; st < 2; ++st) {
    float lf = l[st];
    lf += __shfl_xor(lf, 16);
    lf += __shfl_xor(lf, 32);
    float inv = 1.0f / lf;
#pragma unroll
    for (int dt = 0; dt < 4; ++dt)
#pragma unroll
      for (int r = 0; r < 4; ++r) O[st][dt][r] *= inv;
  }

  {
    bf16x8 pk0 = *(const bf16x8*)&PKl[l15][((g ^ swl) << 3)];
    bf16x8 pk1 = *(const bf16x8*)&PKl[l15][(((4 + g) ^ swl) << 3)];
    bf16x8 ppf[2];
#pragma unroll
    for (int st = 0; st < 2; ++st) {
      f32x4 sp4 = (f32x4){0.f, 0.f, 0.f, 0.f};
      sp4 = mfma16(pk0, qf[st][0], sp4);
      sp4 = mfma16(pk1, qf[st][1], sp4);
      float pm = fmaxf(fmaxf(sp4[0], sp4[1]), fmaxf(sp4[2], sp4[3]));
      pm = fmaxf(pm, __shfl_xor(pm, 16));
      pm = fmaxf(pm, __shfl_xor(pm, 32));
      float pe[4], pl = 0.f;
#pragma unroll
      for (int r = 0; r < 4; ++r) {
        pe[r] = __expf(sp4[r] - pm);
        pl += pe[r];
      }
      pl += __shfl_xor(pl, 16);
      pl += __shfl_xor(pl, 32);
      float cpre = g1[(t0 + 16 * st) >> 2] * bwb / pl;
#pragma unroll
      for (int r = 0; r < 4; ++r) pe[r] *= cpre;
      *(uint2v*)&Pw[l15][g * 4] = (uint2v){pack2(pe[0], pe[1]), pack2(pe[2], pe[3])};
      *(uint2v*)&Pw[l15][16 + g * 4] = (uint2v){0u, 0u};
      ppf[st] = *(const bf16x8*)&Pw[l15][g * 8];
    }
#pragma unroll
    for (int dt = 0; dt < 4; ++dt) {
      bf16x8 pvf = *(const bf16x8*)&PVt[dt * 16 + l15][g * 8];
      O[0][dt] = mfma16(pvf, ppf[0], O[0][dt]);
      O[1][dt] = mfma16(pvf, ppf[1], O[1][dt]);
    }
  }

  __syncthreads();
#pragma unroll
  for (int st = 0; st < 2; ++st) {
    int t = wv * 32 + st * 16 + l15;
#pragma unroll
    for (int dt = 0; dt < 4; ++dt) {
#pragma unroll
      for (int u = 0; u < 2; ++u) {
        unsigned int pw = pack2(O[st][dt][2 * u], O[st][dt][2 * u + 1]);
        int d = dt * 16 + g * 4 + 2 * u;
        *(unsigned int*)&Cb[t * 64 + (((d >> 3) ^ (t & 7)) << 3) + (d & 7)] = pw;
      }
    }
  }
  __syncthreads();
#pragma unroll
  for (int it = 0; it < 4; ++it) {
    int cid = tid + it * 512;
    int j = cid >> 3, c = cid & 7;
    ushort8 row = *(const ushort8*)&Cb[j * 64 + ((c ^ (j & 7)) << 3)];
    *(ushort8*)(comb + slab + (size_t)j * 64 + (c << 3)) = row;
  }
}

// ---------------------------------------------------------------------------
extern "C" void kernel_launch(void* const* d_in, const int* in_sizes, int n_in,
                              void* d_out, int out_size, void* d_ws, size_t ws_size,
                              hipStream_t stream) {
  const float* query = (const float*)d_in[1];
  const float* key = (const float*)d_in[2];
  const float* value = (const float*)d_in[3];
  const float* prefix = (const float*)d_in[4];
  const float* bw = (const float*)d_in[5];
  const float* feat = (const float*)d_in[6];
  const float* noise = (const float*)d_in[7];
  const float* ipw = (const float*)d_in[8];
  const float* ipb = (const float*)d_in[9];
  const float* outw = (const float*)d_in[10];
  const float* outb = (const float*)d_in[11];
  const float* gw = (const float*)d_in[12];
  const float* gb = (const float*)d_in[13];
  float* out = (float*)d_out;

  char* ws = (char*)d_ws;
  const size_t MATB = (size_t)16384 * 1024;  // elements per [16384,1024] matrix
  unsigned short* qb = (unsigned short*)ws;
  unsigned short* kb = qb + MATB;
  unsigned short* vb = kb + MATB;
  unsigned short* cb = vb + MATB;            // attn output; also A-cast scratch
  unsigned short* wip = cb + MATB;           // bf16 in_proj_w [3072,1024]
  unsigned short* wo = wip + (size_t)3072 * 1024;  // bf16 out_w [1024,1024]
  float* g1 = (float*)(wo + (size_t)1024 * 1024);

  gate_kernel<<<64, 64, 0, stream>>>(feat, gw, gb, noise, g1);

  // weight casts (16.8 MB total)
  cast_bf16_kernel<<<1536, 256, 0, stream>>>(ipw, wip, 3072 * 1024 / 8);
  cast_bf16_kernel<<<512, 256, 0, stream>>>(outw, wo, 1024 * 1024 / 8);

  const int N8 = (int)(MATB / 8);
  // q projection (cb used as bf16-A scratch before attn overwrites it)
  cast_bf16_kernel<<<2048, 256, 0, stream>>>(query, cb, N8);
  gemm4b_kernel<0, 1, 0><<<256, 512, 0, stream>>>(cb, wip, ipb, qb);
  // k projection
  cast_bf16_kernel<<<2048, 256, 0, stream>>>(key, cb, N8);
  gemm4b_kernel<0, 0, 0><<<256, 512, 0, stream>>>(cb, wip + (size_t)1024 * 1024, ipb + 1024, kb);
  // v projection
  cast_bf16_kernel<<<2048, 256, 0, stream>>>(value, cb, N8);
  gemm4b_kernel<0, 0, 0><<<256, 512, 0, stream>>>(cb, wip + (size_t)2048 * 1024, ipb + 2048, vb);

  attn_kernel<<<dim3(64, 16), 512, 0, stream>>>(qb, kb, vb, prefix, bw, g1, cb);

  // out-projection reads head-blocked bf16 attn output
  gemm4b_kernel<1, 0, 1><<<256, 512, 0, stream>>>(cb, wo, outb, out);
}

// Round 18
// 253.545 us; speedup vs baseline: 1.1715x; 1.0832x over previous
//
#include <hip/hip_runtime.h>

typedef __attribute__((ext_vector_type(8))) short bf16x8;
typedef __attribute__((ext_vector_type(4))) float f32x4;
typedef __attribute__((ext_vector_type(8))) unsigned short ushort8;
typedef __attribute__((ext_vector_type(4))) unsigned short ushort4v;
typedef __attribute__((ext_vector_type(4))) float float4v;
typedef __attribute__((ext_vector_type(2))) unsigned int uint2v;
typedef __attribute__((ext_vector_type(4))) unsigned int uint4v;

#define TGT 256
#define BSZ 64
#define EMB 1024
#define NH 16
#define HD 64
#define PP 16

__device__ __forceinline__ float b2f(unsigned short u) {
  return __builtin_bit_cast(float, ((unsigned int)u) << 16);
}
__device__ __forceinline__ unsigned short f2b(float f) {
  unsigned int u = __builtin_bit_cast(unsigned int, f);
  u += 0x7fffu + ((u >> 16) & 1u);  // RNE; no NaNs in this workload
  return (unsigned short)(u >> 16);
}
__device__ __forceinline__ unsigned int pack2(float lo, float hi) {
  return (unsigned int)f2b(lo) | ((unsigned int)f2b(hi) << 16);
}
__device__ __forceinline__ f32x4 mfma16(bf16x8 a, bf16x8 b, f32x4 c) {
  return __builtin_amdgcn_mfma_f32_16x16x32_bf16(a, b, c, 0, 0, 0);
}
// async global->LDS, 16B per lane; LDS dest is wave-uniform base + lane*16
__device__ __forceinline__ void gl_lds16(const unsigned short* g, unsigned short* l) {
  __builtin_amdgcn_global_load_lds(
      (const __attribute__((address_space(1))) unsigned int*)g,
      (__attribute__((address_space(3))) unsigned int*)l, 16, 0, 0);
}

// ---------------------------------------------------------------------------
// fused_pre: ONE dispatch replacing {gate, cast(in_proj_w), cast(out_w)}.
// blocks [0,1536): cast ipw -> wip (1536*256 threads = 393216 chunks exactly)
// blocks [1536,2048): cast outw -> wo (512*256 = 131072 chunks exactly)
// blocks [2048,2112): gate for b = blk-2048 on the first wave (64 lanes)
// All parts independent; math identical to the R13 kernels.
// ---------------------------------------------------------------------------
__global__ __launch_bounds__(256) void fused_pre_kernel(
    const float* __restrict__ ipw, unsigned short* __restrict__ wip,
    const float* __restrict__ outw, unsigned short* __restrict__ wo,
    const float* __restrict__ feat, const float* __restrict__ gw,
    const float* __restrict__ gb, const float* __restrict__ noise,
    float* __restrict__ g1) {
  const int blk = blockIdx.x, tid = threadIdx.x;
  if (blk < 2048) {
    const float* in = (blk < 1536) ? ipw : outw;
    unsigned short* out = (blk < 1536) ? wip : wo;
    int i = (blk < 1536) ? (blk * 256 + tid) : ((blk - 1536) * 256 + tid);
    const float4v* p = (const float4v*)(in + (size_t)i * 8);
    float4v v0 = p[0], v1 = p[1];
    ushort8 o = {f2b(v0[0]), f2b(v0[1]), f2b(v0[2]), f2b(v0[3]),
                 f2b(v1[0]), f2b(v1[1]), f2b(v1[2]), f2b(v1[3])};
    *(ushort8*)(out + (size_t)i * 8) = o;
  } else if (tid < 64) {
    const int b = blk - 2048, lane = tid;
    float a0 = 0.f, a1 = 0.f;
    for (int i = lane; i < 512; i += 64) {
      float f = feat[b * 512 + i];
      a0 += f * gw[i];
      a1 += f * gw[512 + i];
    }
#pragma unroll
    for (int off = 32; off >= 1; off >>= 1) {
      a0 += __shfl_xor(a0, off);
      a1 += __shfl_xor(a1, off);
    }
    if (lane == 0) {
      float l0 = (a0 + gb[0] + noise[b * 2 + 0]) * (1.0f / 3.0f);
      float l1 = (a1 + gb[1] + noise[b * 2 + 1]) * (1.0f / 3.0f);
      float mm = fmaxf(l0, l1);
      float e0 = __expf(l0 - mm), e1 = __expf(l1 - mm);
      g1[b] = e1 / (e0 + e1);
    }
  }
}

// ---------------------------------------------------------------------------
// bf16 GEMM: C[16384,1024] = A[16384,1024] @ W[1024,1024]^T + bias
// 256x256 tile, 8 waves, BK=32, 32 K-steps. Counted-vmcnt phase schedule,
// LDS XOR swizzle, setprio, XCD-chunked swizzle. R13-PROVEN (258.6us pass).
//
// A_F32=1: lead-2 reg ring, write-side f2b, rolled 4-step groups with
// LITERAL parity/slot macro args. Correctness anchor: the compiler-exact
// vmcnt before each f2b pack completes its A-regs and (oldest-first, m135)
// all older B gl_lds; manual vmcnt(8) = steady outstanding
// {B(s+2),A(s+2),B(s+3)} is a conservative backstop.
// A_F32=0: gl_lds A with lead-3 4-ring. A_BLOCKED: A head-blocked
// [(b*16+h)][t][d]. OUT_F32=0 writes C head-blocked bf16; =1 row-major f32.
// QSCALE folds attention 1/sqrt(d)=0.125 into the q-projection output.
// ---------------------------------------------------------------------------
#define AOFF(s) (A_BLOCKED ? (((s) >> 1) * 16384 + ((s)&1) * 32) : (s)*32)
#define STAGE_A(s)                                       \
  {                                                      \
    const unsigned short* _ap = abf + AOFF(s);           \
    unsigned short* d = &As[(s) & 3][wl];                \
    gl_lds16(_ap, d);                                    \
    gl_lds16(_ap + aD, d + 4096);                        \
  }
// P = literal parity of t ((t)&1)
#define ISSUE_A32(t, P)                                  \
  {                                                      \
    const float* _p = a32p + (size_t)(t) * 32;           \
    ar[P][0] = *(const float4v*)_p;                      \
    ar[P][1] = *(const float4v*)(_p + 4);                \
    ar[P][2] = *(const float4v*)(_p + 131072);           \
    ar[P][3] = *(const float4v*)(_p + 131072 + 4);       \
  }
#define WRITE_A32(P)                                                    \
  {                                                                     \
    float4v* v = ar[P];                                                 \
    uint4v h0 = {pack2(v[0][0], v[0][1]), pack2(v[0][2], v[0][3]),      \
                 pack2(v[1][0], v[1][1]), pack2(v[1][2], v[1][3])};     \
    uint4v h1 = {pack2(v[2][0], v[2][1]), pack2(v[2][2], v[2][3]),      \
                 pack2(v[3][0], v[3][1]), pack2(v[3][2], v[3][3])};     \
    unsigned short* d = &As[P][swA];                                    \
    *(uint4v*)d = h0;                                                   \
    *(uint4v*)(d + 4096) = h1;                                          \
  }
// SL = literal LDS slot
#define STAGE_B_SLOT(s, SL)                              \
  {                                                      \
    int k0s = (s) * 32;                                  \
    unsigned short* d = &Bs[SL][wl];                     \
    gl_lds16(b0p + k0s, d);                              \
    gl_lds16(b1p + k0s, d + 4096);                       \
  }
#define STAGE_B(s) STAGE_B_SLOT(s, (s)&3)
// f32-A step: PAR = (s)&1 literal, BS = (s)&3 literal
#define G32_STEP(s, PAR, BS, DO_IA, DO_SB, DO_W)                      \
  {                                                                   \
    const unsigned short* Ab = &As[PAR][0];                           \
    const unsigned short* Bb = &Bs[BS][0];                            \
    bf16x8 af[8], bfr[4];                                             \
    _Pragma("unroll") for (int mi = 0; mi < 8; ++mi)                  \
        af[mi] = *(const bf16x8*)&Ab[aoff + mi * 512];                \
    _Pragma("unroll") for (int ni = 0; ni < 2; ++ni)                  \
        bfr[ni] = *(const bf16x8*)&Bb[boff + ni * 512];               \
    if (DO_IA) ISSUE_A32((s) + 2, PAR);  /* (s+2)&1 == PAR */         \
    __builtin_amdgcn_s_barrier();                                     \
    __builtin_amdgcn_s_setprio(1);                                    \
    _Pragma("unroll") for (int mi = 0; mi < 8; ++mi) {                \
      acc[mi][0] = mfma16(af[mi], bfr[0], acc[mi][0]);                \
      acc[mi][1] = mfma16(af[mi], bfr[1], acc[mi][1]);                \
    }                                                                 \
    __builtin_amdgcn_s_setprio(0);                                    \
    __builtin_amdgcn_s_barrier();                                     \
    _Pragma("unroll") for (int ni = 2; ni < 4; ++ni)                  \
        bfr[ni] = *(const bf16x8*)&Bb[boff + ni * 512];               \
    if (DO_SB) STAGE_B_SLOT((s) + 3, ((BS) + 3) & 3);                 \
    __builtin_amdgcn_s_barrier();                                     \
    __builtin_amdgcn_s_setprio(1);                                    \
    _Pragma("unroll") for (int mi = 0; mi < 8; ++mi) {                \
      acc[mi][2] = mfma16(af[mi], bfr[2], acc[mi][2]);                \
      acc[mi][3] = mfma16(af[mi], bfr[3], acc[mi][3]);                \
    }                                                                 \
    __builtin_amdgcn_s_setprio(0);                                    \
    if (DO_W) WRITE_A32((PAR) ^ 1); /* writes A(s+1) */               \
  }
// bf16-A step (proven R4 path)
#define GEMM_STEP(s, DO_STAGE)                                        \
  {                                                                   \
    const unsigned short* Ab = &As[(s) & 3][0];                       \
    const unsigned short* Bb = &Bs[(s) & 3][0];                       \
    bf16x8 af[8], bfr[4];                                             \
    _Pragma("unroll") for (int mi = 0; mi < 8; ++mi)                  \
        af[mi] = *(const bf16x8*)&Ab[aoff + mi * 512];                \
    _Pragma("unroll") for (int ni = 0; ni < 2; ++ni)                  \
        bfr[ni] = *(const bf16x8*)&Bb[boff + ni * 512];               \
    if (DO_STAGE) STAGE_A((s) + 3);                                   \
    __builtin_amdgcn_s_barrier();                                     \
    __builtin_amdgcn_s_setprio(1);                                    \
    _Pragma("unroll") for (int mi = 0; mi < 8; ++mi) {                \
      acc[mi][0] = mfma16(af[mi], bfr[0], acc[mi][0]);                \
      acc[mi][1] = mfma16(af[mi], bfr[1], acc[mi][1]);                \
    }                                                                 \
    __builtin_amdgcn_s_setprio(0);                                    \
    __builtin_amdgcn_s_barrier();                                     \
    _Pragma("unroll") for (int ni = 2; ni < 4; ++ni)                  \
        bfr[ni] = *(const bf16x8*)&Bb[boff + ni * 512];               \
    if (DO_STAGE) STAGE_B((s) + 3);                                   \
    __builtin_amdgcn_s_barrier();                                     \
    __builtin_amdgcn_s_setprio(1);                                    \
    _Pragma("unroll") for (int mi = 0; mi < 8; ++mi) {                \
      acc[mi][2] = mfma16(af[mi], bfr[2], acc[mi][2]);                \
      acc[mi][3] = mfma16(af[mi], bfr[3], acc[mi][3]);                \
    }                                                                 \
    __builtin_amdgcn_s_setprio(0);                                    \
  }
#define STEP_WAIT(cntstr)                                \
  asm volatile("s_waitcnt " cntstr ::: "memory");        \
  __builtin_amdgcn_sched_barrier(0);                     \
  __builtin_amdgcn_s_barrier();

template <int OUT_F32, int QSCALE, int A_BLOCKED, int A_F32>
__global__ __launch_bounds__(512, 2) void gemm256_kernel(
    const void* __restrict__ Av, const unsigned short* __restrict__ W,
    const float* __restrict__ bias, void* __restrict__ Cv) {
  constexpr int K = 1024, N = 1024;
  __shared__ __attribute__((aligned(16))) unsigned short As[(A_F32 ? 2 : 4)][8192];
  __shared__ __attribute__((aligned(16))) unsigned short Bs[4][8192];  // 64 KB
  const int tid = threadIdx.x;
  const int wv = tid >> 6, lane = tid & 63;
  const int l15 = lane & 15, kg = lane >> 4;
  const int bid = blockIdx.x;
  const int cpx = gridDim.x >> 3;
  const int wg = (bid & 7) * cpx + (bid >> 3);
  const int m0 = (wg >> 2) * 256, n0 = (wg & 3) * 256;
  const int wmL = (wv >> 2) * 128, wnL = (wv & 3) * 64;

  const int sr = wv * 16 + (lane >> 2);                      // row in 128-half
  const int sc = ((lane & 3) * 8) ^ (((sr >> 1) & 3) << 3);  // pre-swizzled col
  const int srg = m0 + sr;
  const unsigned short* abf;  // bf16-A base (A_F32==0)
  if constexpr (A_BLOCKED)
    abf = (const unsigned short*)Av + (size_t)(srg & 63) * 262144 + (srg >> 6) * 64 + sc;
  else
    abf = (const unsigned short*)Av + (size_t)srg * K + sc;
  const int aD = A_BLOCKED ? 128 : 128 * K;
  // f32-A (A_F32==1): LINEAR source col; swizzle applied on the ds_write side
  const float* a32p = (const float*)Av + (size_t)srg * K + (lane & 3) * 8;
  const int swA = sr * 32 + (((lane & 3) ^ ((sr >> 1) & 3)) << 3);
  float4v ar[2][4];  // lead-2 reg ring (32 VGPR; literal-indexed)
  const unsigned short* b0p = W + (size_t)(n0 + sr) * K + sc;
  const unsigned short* b1p = b0p + (size_t)128 * K;
  const int wl = wv * 512;

  const int x = ((l15 >> 1) & 3) << 3;
  const int aoff = (wmL + l15) * 32 + ((kg * 8) ^ x);
  const int boff = (wnL + l15) * 32 + ((kg * 8) ^ x);

  f32x4 acc[8][4];
#pragma unroll
  for (int i = 0; i < 8; ++i)
#pragma unroll
    for (int j = 0; j < 4; ++j) acc[i][j] = (f32x4){0.f, 0.f, 0.f, 0.f};

  if constexpr (A_F32) {
    // Prologue (R11-proven counting): A(0),B(0),A(1),B(1),B(2); write A(0).
    // Compiler wait drains A(0); vmcnt(8) completes B(0) (leaves A1,B1,B2=8).
    ISSUE_A32(0, 0); STAGE_B(0); ISSUE_A32(1, 1); STAGE_B(1); STAGE_B(2);
    WRITE_A32(0);
    STEP_WAIT("vmcnt(8) lgkmcnt(0)")
    // Rolled main loop: 7 x 4 steps (slot pattern period 4).
#pragma unroll 1
    for (int sb = 0; sb < 28; sb += 4) {
      G32_STEP(sb + 0, 0, 0, 1, 1, 1);
      STEP_WAIT("vmcnt(8) lgkmcnt(0)")
      G32_STEP(sb + 1, 1, 1, 1, 1, 1);
      STEP_WAIT("vmcnt(8) lgkmcnt(0)")
      G32_STEP(sb + 2, 0, 2, 1, 1, 1);
      STEP_WAIT("vmcnt(8) lgkmcnt(0)")
      G32_STEP(sb + 3, 1, 3, 1, 1, 1);
      STEP_WAIT("vmcnt(8) lgkmcnt(0)")
    }
    // Tail s=28..31 (audited counting)
    G32_STEP(28, 0, 0, 1, 1, 1);
    STEP_WAIT("vmcnt(8) lgkmcnt(0)")
    G32_STEP(29, 1, 1, 1, 0, 1);  // issues A(31); writes A(30)
    STEP_WAIT("vmcnt(8) lgkmcnt(0)")
    G32_STEP(30, 0, 2, 0, 0, 1);  // writes A(31); compiler wait drains all
    STEP_WAIT("vmcnt(0) lgkmcnt(0)")
    G32_STEP(31, 1, 3, 0, 0, 0);
  } else {
    STAGE_A(0); STAGE_B(0); STAGE_A(1); STAGE_B(1); STAGE_A(2); STAGE_B(2);
    STEP_WAIT("vmcnt(8)")
    for (int s = 0; s < 29; ++s) {
      GEMM_STEP(s, 1);
      STEP_WAIT("vmcnt(8)")
    }
    GEMM_STEP(29, 0);
    STEP_WAIT("vmcnt(4)")
    GEMM_STEP(30, 0);
    STEP_WAIT("vmcnt(0)")
    GEMM_STEP(31, 0);
  }

#pragma unroll
  for (int mi = 0; mi < 8; ++mi) {
#pragma unroll
    for (int ni = 0; ni < 4; ++ni) {
      int col = n0 + wnL + ni * 16 + l15;
      float bcol = bias[col];
#pragma unroll
      for (int r = 0; r < 4; ++r) {
        int row = m0 + wmL + mi * 16 + kg * 4 + r;
        float v = acc[mi][ni][r] + bcol;
        if constexpr (QSCALE) v *= 0.125f;
        if constexpr (OUT_F32) {
          ((float*)Cv)[(size_t)row * N + col] = v;
        } else {
          // head-blocked store: [(b*16+h)][t][d]
          int t = row >> 6, bb = row & 63, hh = col >> 6, dd = col & 63;
          ((unsigned short*)Cv)[(size_t)((bb * 16 + hh) * 256 + t) * 64 + dd] = f2b(v);
        }
      }
    }
  }
}

// ---------------------------------------------------------------------------
// MFMA attention per (b,h) — EXACT R4/R13-proven kernel.
// q/k/v/comb HEAD-BLOCKED [(b*16+h)][t][d]; 8 waves x 32 t-rows,
// strip-merged; natural-log softmax via __expf; pack2/f2b packing;
// T13 defer-rescale; V^T gran swizzle.
// combined = attn + g1[t>>2]*bw[b]*attn_pre (uses g0+g1==1).
// Q pre-scaled by 0.125 in the q-projection GEMM.
// ---------------------------------------------------------------------------
__global__ __launch_bounds__(512) void attn_kernel(
    const unsigned short* __restrict__ qb, const unsigned short* __restrict__ kb,
    const unsigned short* __restrict__ vb, const float* __restrict__ prefix,
    const float* __restrict__ bw, const float* __restrict__ g1,
    unsigned short* __restrict__ comb) {
  const int b = blockIdx.x, h = blockIdx.y;
  __shared__ __attribute__((aligned(16))) unsigned short Kl[256][64];
  __shared__ __attribute__((aligned(16))) unsigned short Vt[64 * 256];
  __shared__ __attribute__((aligned(16))) unsigned short PKl[16][64];
  __shared__ __attribute__((aligned(16))) unsigned short PVt[64][32];
  __shared__ __attribute__((aligned(16))) unsigned short Plds[8][16][40];
  unsigned short* Cb = &Kl[0][0];
  const int tid = threadIdx.x;
  const int wv = tid >> 6, lane = tid & 63;
  const size_t slab = (size_t)(b * NH + h) * 16384;

#pragma unroll
  for (int it = 0; it < 4; ++it) {
    int cid = tid + it * 512;
    int j = cid >> 3, c = cid & 7;
    gl_lds16(kb + slab + (size_t)j * 64 + ((c ^ (j & 7)) << 3),
             &Kl[0][0] + (size_t)(it * 512 + wv * 64) * 8);
    ushort8 vv = *(const ushort8*)(vb + slab + (size_t)j * 64 + (c << 3));
#pragma unroll
    for (int i = 0; i < 8; ++i) {
      int gran = (j >> 3) ^ i ^ c;
      Vt[(c * 8 + i) * 256 + gran * 8 + (j & 7)] = vv[i];
    }
  }
  if (tid < 256) {
    int arr = tid >> 7, cid = tid & 127;
    int sp = cid >> 3, c = cid & 7;
    const float* src = prefix + ((size_t)(b * 2 + arr) * PP + sp) * EMB + h * HD + c * 8;
    float4v v0 = *(const float4v*)src;
    float4v v1 = *(const float4v*)(src + 4);
    if (arr == 0) {
      ushort8 o = {f2b(v0[0]), f2b(v0[1]), f2b(v0[2]), f2b(v0[3]),
                   f2b(v1[0]), f2b(v1[1]), f2b(v1[2]), f2b(v1[3])};
      *(ushort8*)&PKl[sp][((c ^ (sp & 7)) << 3)] = o;
    } else {
#pragma unroll
      for (int i = 0; i < 8; ++i)
        PVt[c * 8 + i][sp] = f2b(i < 4 ? v0[i] : v1[i - 4]);
    }
  } else if (tid < 384) {
    int cid = tid - 256;
    *(ushort8*)&PVt[cid >> 1][16 + (cid & 1) * 8] = (ushort8){0, 0, 0, 0, 0, 0, 0, 0};
  }
  __syncthreads();

  const int l15 = lane & 15, g = lane >> 4;
  const int swl = l15 & 7;
  const float bwb = bw[b];
  unsigned short(&Pw)[16][40] = Plds[wv];

  const int t0 = wv * 32 + l15;
  const size_t qbase = slab + (size_t)t0 * 64;
  bf16x8 qf[2][2];
  qf[0][0] = *(const bf16x8*)(qb + qbase + g * 8);
  qf[0][1] = *(const bf16x8*)(qb + qbase + 32 + g * 8);
  qf[1][0] = *(const bf16x8*)(qb + qbase + 1024 + g * 8);
  qf[1][1] = *(const bf16x8*)(qb + qbase + 1024 + 32 + g * 8);

  f32x4 O[2][4];
#pragma unroll
  for (int st = 0; st < 2; ++st)
#pragma unroll
    for (int dt = 0; dt < 4; ++dt) O[st][dt] = (f32x4){0.f, 0.f, 0.f, 0.f};
  float m[2] = {-3.0e38f, -3.0e38f}, l[2] = {0.f, 0.f};

#pragma unroll
  for (int ch = 0; ch < 8; ++ch) {
    const int rA = ch * 32 + l15, rB = rA + 16;
    bf16x8 ka0 = *(const bf16x8*)&Kl[rA][((g ^ swl) << 3)];
    bf16x8 ka1 = *(const bf16x8*)&Kl[rA][(((4 + g) ^ swl) << 3)];
    bf16x8 kb0 = *(const bf16x8*)&Kl[rB][((g ^ swl) << 3)];
    bf16x8 kb1 = *(const bf16x8*)&Kl[rB][(((4 + g) ^ swl) << 3)];
    f32x4 s[2][2];
#pragma unroll
    for (int st = 0; st < 2; ++st) {
      s[st][0] = (f32x4){0.f, 0.f, 0.f, 0.f};
      s[st][1] = (f32x4){0.f, 0.f, 0.f, 0.f};
      s[st][0] = mfma16(ka0, qf[st][0], s[st][0]);
      s[st][0] = mfma16(ka1, qf[st][1], s[st][0]);
      s[st][1] = mfma16(kb0, qf[st][0], s[st][1]);
      s[st][1] = mfma16(kb1, qf[st][1], s[st][1]);
    }
    bf16x8 pf[2];
#pragma unroll
    for (int st = 0; st < 2; ++st) {
      f32x4 sa = s[st][0], sb = s[st][1];
      float mx = fmaxf(fmaxf(fmaxf(sa[0], sa[1]), fmaxf(sa[2], sa[3])),
                       fmaxf(fmaxf(sb[0], sb[1]), fmaxf(sb[2], sb[3])));
      mx = fmaxf(mx, __shfl_xor(mx, 16));
      mx = fmaxf(mx, __shfl_xor(mx, 32));
      // T13 defer-rescale: only rescale when some row grew by > 8
      if (__ballot(mx > m[st] + 8.0f) != 0ull) {
        float mn = fmaxf(m[st], mx);
        float f = __expf(m[st] - mn);
        m[st] = mn;
        l[st] *= f;
#pragma unroll
        for (int dt = 0; dt < 4; ++dt)
#pragma unroll
          for (int r = 0; r < 4; ++r) O[st][dt][r] *= f;
      }
      float pA[4], pB[4];
#pragma unroll
      for (int r = 0; r < 4; ++r) {
        pA[r] = __expf(sa[r] - m[st]);
        pB[r] = __expf(sb[r] - m[st]);
      }
      uint2v wa = {pack2(pA[0], pA[1]), pack2(pA[2], pA[3])};
      uint2v wb2 = {pack2(pB[0], pB[1]), pack2(pB[2], pB[3])};
      *(uint2v*)&Pw[l15][g * 4] = wa;
      *(uint2v*)&Pw[l15][16 + g * 4] = wb2;
      // l accumulates the ROUNDED p so normalization compensates quantization
      float sloc = b2f((unsigned short)(wa[0] & 0xffff)) + b2f((unsigned short)(wa[0] >> 16)) +
                   b2f((unsigned short)(wa[1] & 0xffff)) + b2f((unsigned short)(wa[1] >> 16)) +
                   b2f((unsigned short)(wb2[0] & 0xffff)) + b2f((unsigned short)(wb2[0] >> 16)) +
                   b2f((unsigned short)(wb2[1] & 0xffff)) + b2f((unsigned short)(wb2[1] >> 16));
      l[st] += sloc;
      // read own B-frag before next strip overwrites the tile (in-order DS)
      pf[st] = *(const bf16x8*)&Pw[l15][g * 8];
    }
#pragma unroll
    for (int dt = 0; dt < 4; ++dt) {
      const int drow = dt * 16 + l15;
      const int gran = (ch * 4 + g) ^ (drow & 7) ^ (drow >> 3);
      bf16x8 vf = *(const bf16x8*)&Vt[drow * 256 + gran * 8];
      O[0][dt] = mfma16(vf, pf[0], O[0][dt]);
      O[1][dt] = mfma16(vf, pf[1], O[1][dt]);
    }
  }

#pragma unroll
  for (int st = 0; st < 2; ++st) {
    float lf = l[st];
    lf += __shfl_xor(lf, 16);
    lf += __shfl_xor(lf, 32);
    float inv = 1.0f / lf;
#pragma unroll
    for (int dt = 0; dt < 4; ++dt)
#pragma unroll
      for (int r = 0; r < 4; ++r) O[st][dt][r] *= inv;
  }

  // prefix attention (s=16 zero-padded to 32), scaled by g1*bw/sum
  {
    bf16x8 pk0 = *(const bf16x8*)&PKl[l15][((g ^ swl) << 3)];
    bf16x8 pk1 = *(const bf16x8*)&PKl[l15][(((4 + g) ^ swl) << 3)];
    bf16x8 ppf[2];
#pragma unroll
    for (int st = 0; st < 2; ++st) {
      f32x4 sp4 = (f32x4){0.f, 0.f, 0.f, 0.f};
      sp4 = mfma16(pk0, qf[st][0], sp4);
      sp4 = mfma16(pk1, qf[st][1], sp4);
      float pm = fmaxf(fmaxf(sp4[0], sp4[1]), fmaxf(sp4[2], sp4[3]));
      pm = fmaxf(pm, __shfl_xor(pm, 16));
      pm = fmaxf(pm, __shfl_xor(pm, 32));
      float pe[4], pl = 0.f;
#pragma unroll
      for (int r = 0; r < 4; ++r) {
        pe[r] = __expf(sp4[r] - pm);
        pl += pe[r];
      }
      pl += __shfl_xor(pl, 16);
      pl += __shfl_xor(pl, 32);
      float cpre = g1[(t0 + 16 * st) >> 2] * bwb / pl;
#pragma unroll
      for (int r = 0; r < 4; ++r) pe[r] *= cpre;
      *(uint2v*)&Pw[l15][g * 4] = (uint2v){pack2(pe[0], pe[1]), pack2(pe[2], pe[3])};
      *(uint2v*)&Pw[l15][16 + g * 4] = (uint2v){0u, 0u};
      ppf[st] = *(const bf16x8*)&Pw[l15][g * 8];
    }
#pragma unroll
    for (int dt = 0; dt < 4; ++dt) {
      bf16x8 pvf = *(const bf16x8*)&PVt[dt * 16 + l15][g * 8];
      O[0][dt] = mfma16(pvf, ppf[0], O[0][dt]);
      O[1][dt] = mfma16(pvf, ppf[1], O[1][dt]);
    }
  }

  __syncthreads();  // all waves done reading Kl before bounce overlays it
#pragma unroll
  for (int st = 0; st < 2; ++st) {
    int t = wv * 32 + st * 16 + l15;
#pragma unroll
    for (int dt = 0; dt < 4; ++dt) {
#pragma unroll
      for (int u = 0; u < 2; ++u) {
        unsigned int pw = pack2(O[st][dt][2 * u], O[st][dt][2 * u + 1]);
        int d = dt * 16 + g * 4 + 2 * u;
        *(unsigned int*)&Cb[t * 64 + (((d >> 3) ^ (t & 7)) << 3) + (d & 7)] = pw;
      }
    }
  }
  __syncthreads();
#pragma unroll
  for (int it = 0; it < 4; ++it) {
    int cid = tid + it * 512;
    int j = cid >> 3, c = cid & 7;
    ushort8 row = *(const ushort8*)&Cb[j * 64 + ((c ^ (j & 7)) << 3)];
    *(ushort8*)(comb + slab + (size_t)j * 64 + (c << 3)) = row;
  }
}

// ---------------------------------------------------------------------------
extern "C" void kernel_launch(void* const* d_in, const int* in_sizes, int n_in,
                              void* d_out, int out_size, void* d_ws, size_t ws_size,
                              hipStream_t stream) {
  const float* query = (const float*)d_in[1];
  const float* key = (const float*)d_in[2];
  const float* value = (const float*)d_in[3];
  const float* prefix = (const float*)d_in[4];
  const float* bw = (const float*)d_in[5];
  const float* feat = (const float*)d_in[6];
  const float* noise = (const float*)d_in[7];
  const float* ipw = (const float*)d_in[8];
  const float* ipb = (const float*)d_in[9];
  const float* outw = (const float*)d_in[10];
  const float* outb = (const float*)d_in[11];
  const float* gw = (const float*)d_in[12];
  const float* gb = (const float*)d_in[13];
  float* out = (float*)d_out;

  char* ws = (char*)d_ws;
  const size_t MATB = (size_t)16384 * 1024;  // elements per [16384,1024] matrix
  unsigned short* qb = (unsigned short*)ws;
  unsigned short* kb = qb + MATB;
  unsigned short* vb = kb + MATB;
  unsigned short* cb = vb + MATB;            // attn output (head-blocked)
  unsigned short* wip = cb + MATB;           // bf16 in_proj_w [3072,1024]
  unsigned short* wo = wip + (size_t)3072 * 1024;  // bf16 out_w [1024,1024]
  float* g1 = (float*)(wo + (size_t)1024 * 1024);

  // gate + both weight casts in ONE dispatch
  fused_pre_kernel<<<2112, 256, 0, stream>>>(ipw, wip, outw, wo, feat, gw, gb,
                                             noise, g1);

  // projections read f32 inputs directly (f2b write-side staging, lead-2,
  // rolled main loop) — R13-proven
  gemm256_kernel<0, 1, 0, 1><<<256, 512, 0, stream>>>(query, wip, ipb, qb);
  gemm256_kernel<0, 0, 0, 1><<<256, 512, 0, stream>>>(key, wip + (size_t)1024 * 1024, ipb + 1024, kb);
  gemm256_kernel<0, 0, 0, 1><<<256, 512, 0, stream>>>(value, wip + (size_t)2048 * 1024, ipb + 2048, vb);

  attn_kernel<<<dim3(64, 16), 512, 0, stream>>>(qb, kb, vb, prefix, bw, g1, cb);

  // out-projection reads head-blocked bf16 attn output (proven gl_lds path)
  gemm256_kernel<1, 0, 1, 0><<<256, 512, 0, stream>>>(cb, wo, outb, out);
}

// Round 19
// 252.170 us; speedup vs baseline: 1.1779x; 1.0055x over previous
//
#include <hip/hip_runtime.h>

typedef __attribute__((ext_vector_type(8))) short bf16x8;
typedef __attribute__((ext_vector_type(4))) float f32x4;
typedef __attribute__((ext_vector_type(8))) unsigned short ushort8;
typedef __attribute__((ext_vector_type(4))) unsigned short ushort4v;
typedef __attribute__((ext_vector_type(4))) float float4v;
typedef __attribute__((ext_vector_type(2))) unsigned int uint2v;
typedef __attribute__((ext_vector_type(4))) unsigned int uint4v;

#define TGT 256
#define BSZ 64
#define EMB 1024
#define NH 16
#define HD 64
#define PP 16
// 0.125 (1/sqrt(64)) * log2(e): softmax runs in exp2 domain (R19 isolation;
// cvtpk was the R5-R9 culprit per the R9 bisect, exp2-domain never tested alone)
#define QK_SCALE 0.18033688011112042f

__device__ __forceinline__ float b2f(unsigned short u) {
  return __builtin_bit_cast(float, ((unsigned int)u) << 16);
}
__device__ __forceinline__ unsigned short f2b(float f) {
  unsigned int u = __builtin_bit_cast(unsigned int, f);
  u += 0x7fffu + ((u >> 16) & 1u);  // RNE; no NaNs in this workload
  return (unsigned short)(u >> 16);
}
__device__ __forceinline__ unsigned int pack2(float lo, float hi) {
  return (unsigned int)f2b(lo) | ((unsigned int)f2b(hi) << 16);
}
// exp2 via COMPILER-EMITTED v_exp_f32 (TRANS hazards handled by compiler)
__device__ __forceinline__ float exp2s(float x) {
#if __has_builtin(__builtin_amdgcn_exp2f)
  return __builtin_amdgcn_exp2f(x);
#else
  return exp2f(x);
#endif
}
__device__ __forceinline__ f32x4 mfma16(bf16x8 a, bf16x8 b, f32x4 c) {
  return __builtin_amdgcn_mfma_f32_16x16x32_bf16(a, b, c, 0, 0, 0);
}
// async global->LDS, 16B per lane; LDS dest is wave-uniform base + lane*16
__device__ __forceinline__ void gl_lds16(const unsigned short* g, unsigned short* l) {
  __builtin_amdgcn_global_load_lds(
      (const __attribute__((address_space(1))) unsigned int*)g,
      (__attribute__((address_space(3))) unsigned int*)l, 16, 0, 0);
}

// ---------------------------------------------------------------------------
// fused_pre: ONE dispatch replacing {gate, cast(in_proj_w), cast(out_w)}.
// blocks [0,1536): cast ipw -> wip; [1536,2048): cast outw -> wo;
// [2048,2112): gate for b = blk-2048 on the first wave.
// ---------------------------------------------------------------------------
__global__ __launch_bounds__(256) void fused_pre_kernel(
    const float* __restrict__ ipw, unsigned short* __restrict__ wip,
    const float* __restrict__ outw, unsigned short* __restrict__ wo,
    const float* __restrict__ feat, const float* __restrict__ gw,
    const float* __restrict__ gb, const float* __restrict__ noise,
    float* __restrict__ g1) {
  const int blk = blockIdx.x, tid = threadIdx.x;
  if (blk < 2048) {
    const float* in = (blk < 1536) ? ipw : outw;
    unsigned short* out = (blk < 1536) ? wip : wo;
    int i = (blk < 1536) ? (blk * 256 + tid) : ((blk - 1536) * 256 + tid);
    const float4v* p = (const float4v*)(in + (size_t)i * 8);
    float4v v0 = p[0], v1 = p[1];
    ushort8 o = {f2b(v0[0]), f2b(v0[1]), f2b(v0[2]), f2b(v0[3]),
                 f2b(v1[0]), f2b(v1[1]), f2b(v1[2]), f2b(v1[3])};
    *(ushort8*)(out + (size_t)i * 8) = o;
  } else if (tid < 64) {
    const int b = blk - 2048, lane = tid;
    float a0 = 0.f, a1 = 0.f;
    for (int i = lane; i < 512; i += 64) {
      float f = feat[b * 512 + i];
      a0 += f * gw[i];
      a1 += f * gw[512 + i];
    }
#pragma unroll
    for (int off = 32; off >= 1; off >>= 1) {
      a0 += __shfl_xor(a0, off);
      a1 += __shfl_xor(a1, off);
    }
    if (lane == 0) {
      float l0 = (a0 + gb[0] + noise[b * 2 + 0]) * (1.0f / 3.0f);
      float l1 = (a1 + gb[1] + noise[b * 2 + 1]) * (1.0f / 3.0f);
      float mm = fmaxf(l0, l1);
      float e0 = __expf(l0 - mm), e1 = __expf(l1 - mm);
      g1[b] = e1 / (e0 + e1);
    }
  }
}

// ---------------------------------------------------------------------------
// bf16 GEMM: C[16384,1024] = A[16384,1024] @ W[1024,1024]^T + bias
// 256x256 tile, 8 waves, BK=32, 32 K-steps. R13/R18-PROVEN schedule.
// A_F32=1: lead-2 reg ring, write-side f2b, rolled 4-step groups (literal
// parity/slot). A_F32=0: gl_lds lead-3 4-ring. A_BLOCKED: head-blocked A.
// OUT_F32=0 writes head-blocked bf16; =1 row-major f32.
// QSCALE folds QK_SCALE (1/sqrt(d) * log2e) into the q-projection output.
// ---------------------------------------------------------------------------
#define AOFF(s) (A_BLOCKED ? (((s) >> 1) * 16384 + ((s)&1) * 32) : (s)*32)
#define STAGE_A(s)                                       \
  {                                                      \
    const unsigned short* _ap = abf + AOFF(s);           \
    unsigned short* d = &As[(s) & 3][wl];                \
    gl_lds16(_ap, d);                                    \
    gl_lds16(_ap + aD, d + 4096);                        \
  }
#define ISSUE_A32(t, P)                                  \
  {                                                      \
    const float* _p = a32p + (size_t)(t) * 32;           \
    ar[P][0] = *(const float4v*)_p;                      \
    ar[P][1] = *(const float4v*)(_p + 4);                \
    ar[P][2] = *(const float4v*)(_p + 131072);           \
    ar[P][3] = *(const float4v*)(_p + 131072 + 4);       \
  }
#define WRITE_A32(P)                                                    \
  {                                                                     \
    float4v* v = ar[P];                                                 \
    uint4v h0 = {pack2(v[0][0], v[0][1]), pack2(v[0][2], v[0][3]),      \
                 pack2(v[1][0], v[1][1]), pack2(v[1][2], v[1][3])};     \
    uint4v h1 = {pack2(v[2][0], v[2][1]), pack2(v[2][2], v[2][3]),      \
                 pack2(v[3][0], v[3][1]), pack2(v[3][2], v[3][3])};     \
    unsigned short* d = &As[P][swA];                                    \
    *(uint4v*)d = h0;                                                   \
    *(uint4v*)(d + 4096) = h1;                                          \
  }
#define STAGE_B_SLOT(s, SL)                              \
  {                                                      \
    int k0s = (s) * 32;                                  \
    unsigned short* d = &Bs[SL][wl];                     \
    gl_lds16(b0p + k0s, d);                              \
    gl_lds16(b1p + k0s, d + 4096);                       \
  }
#define STAGE_B(s) STAGE_B_SLOT(s, (s)&3)
#define G32_STEP(s, PAR, BS, DO_IA, DO_SB, DO_W)                      \
  {                                                                   \
    const unsigned short* Ab = &As[PAR][0];                           \
    const unsigned short* Bb = &Bs[BS][0];                            \
    bf16x8 af[8], bfr[4];                                             \
    _Pragma("unroll") for (int mi = 0; mi < 8; ++mi)                  \
        af[mi] = *(const bf16x8*)&Ab[aoff + mi * 512];                \
    _Pragma("unroll") for (int ni = 0; ni < 2; ++ni)                  \
        bfr[ni] = *(const bf16x8*)&Bb[boff + ni * 512];               \
    if (DO_IA) ISSUE_A32((s) + 2, PAR);                               \
    __builtin_amdgcn_s_barrier();                                     \
    __builtin_amdgcn_s_setprio(1);                                    \
    _Pragma("unroll") for (int mi = 0; mi < 8; ++mi) {                \
      acc[mi][0] = mfma16(af[mi], bfr[0], acc[mi][0]);                \
      acc[mi][1] = mfma16(af[mi], bfr[1], acc[mi][1]);                \
    }                                                                 \
    __builtin_amdgcn_s_setprio(0);                                    \
    __builtin_amdgcn_s_barrier();                                     \
    _Pragma("unroll") for (int ni = 2; ni < 4; ++ni)                  \
        bfr[ni] = *(const bf16x8*)&Bb[boff + ni * 512];               \
    if (DO_SB) STAGE_B_SLOT((s) + 3, ((BS) + 3) & 3);                 \
    __builtin_amdgcn_s_barrier();                                     \
    __builtin_amdgcn_s_setprio(1);                                    \
    _Pragma("unroll") for (int mi = 0; mi < 8; ++mi) {                \
      acc[mi][2] = mfma16(af[mi], bfr[2], acc[mi][2]);                \
      acc[mi][3] = mfma16(af[mi], bfr[3], acc[mi][3]);                \
    }                                                                 \
    __builtin_amdgcn_s_setprio(0);                                    \
    if (DO_W) WRITE_A32((PAR) ^ 1);                                   \
  }
#define GEMM_STEP(s, DO_STAGE)                                        \
  {                                                                   \
    const unsigned short* Ab = &As[(s) & 3][0];                       \
    const unsigned short* Bb = &Bs[(s) & 3][0];                       \
    bf16x8 af[8], bfr[4];                                             \
    _Pragma("unroll") for (int mi = 0; mi < 8; ++mi)                  \
        af[mi] = *(const bf16x8*)&Ab[aoff + mi * 512];                \
    _Pragma("unroll") for (int ni = 0; ni < 2; ++ni)                  \
        bfr[ni] = *(const bf16x8*)&Bb[boff + ni * 512];               \
    if (DO_STAGE) STAGE_A((s) + 3);                                   \
    __builtin_amdgcn_s_barrier();                                     \
    __builtin_amdgcn_s_setprio(1);                                    \
    _Pragma("unroll") for (int mi = 0; mi < 8; ++mi) {                \
      acc[mi][0] = mfma16(af[mi], bfr[0], acc[mi][0]);                \
      acc[mi][1] = mfma16(af[mi], bfr[1], acc[mi][1]);                \
    }                                                                 \
    __builtin_amdgcn_s_setprio(0);                                    \
    __builtin_amdgcn_s_barrier();                                     \
    _Pragma("unroll") for (int ni = 2; ni < 4; ++ni)                  \
        bfr[ni] = *(const bf16x8*)&Bb[boff + ni * 512];               \
    if (DO_STAGE) STAGE_B((s) + 3);                                   \
    __builtin_amdgcn_s_barrier();                                     \
    __builtin_amdgcn_s_setprio(1);                                    \
    _Pragma("unroll") for (int mi = 0; mi < 8; ++mi) {                \
      acc[mi][2] = mfma16(af[mi], bfr[2], acc[mi][2]);                \
      acc[mi][3] = mfma16(af[mi], bfr[3], acc[mi][3]);                \
    }                                                                 \
    __builtin_amdgcn_s_setprio(0);                                    \
  }
#define STEP_WAIT(cntstr)                                \
  asm volatile("s_waitcnt " cntstr ::: "memory");        \
  __builtin_amdgcn_sched_barrier(0);                     \
  __builtin_amdgcn_s_barrier();

template <int OUT_F32, int QSCALE, int A_BLOCKED, int A_F32>
__global__ __launch_bounds__(512, 2) void gemm256_kernel(
    const void* __restrict__ Av, const unsigned short* __restrict__ W,
    const float* __restrict__ bias, void* __restrict__ Cv) {
  constexpr int K = 1024, N = 1024;
  __shared__ __attribute__((aligned(16))) unsigned short As[(A_F32 ? 2 : 4)][8192];
  __shared__ __attribute__((aligned(16))) unsigned short Bs[4][8192];  // 64 KB
  const int tid = threadIdx.x;
  const int wv = tid >> 6, lane = tid & 63;
  const int l15 = lane & 15, kg = lane >> 4;
  const int bid = blockIdx.x;
  const int cpx = gridDim.x >> 3;
  const int wg = (bid & 7) * cpx + (bid >> 3);
  const int m0 = (wg >> 2) * 256, n0 = (wg & 3) * 256;
  const int wmL = (wv >> 2) * 128, wnL = (wv & 3) * 64;

  const int sr = wv * 16 + (lane >> 2);                      // row in 128-half
  const int sc = ((lane & 3) * 8) ^ (((sr >> 1) & 3) << 3);  // pre-swizzled col
  const int srg = m0 + sr;
  const unsigned short* abf;  // bf16-A base (A_F32==0)
  if constexpr (A_BLOCKED)
    abf = (const unsigned short*)Av + (size_t)(srg & 63) * 262144 + (srg >> 6) * 64 + sc;
  else
    abf = (const unsigned short*)Av + (size_t)srg * K + sc;
  const int aD = A_BLOCKED ? 128 : 128 * K;
  // f32-A (A_F32==1): LINEAR source col; swizzle applied on the ds_write side
  const float* a32p = (const float*)Av + (size_t)srg * K + (lane & 3) * 8;
  const int swA = sr * 32 + (((lane & 3) ^ ((sr >> 1) & 3)) << 3);
  float4v ar[2][4];  // lead-2 reg ring (literal-indexed)
  const unsigned short* b0p = W + (size_t)(n0 + sr) * K + sc;
  const unsigned short* b1p = b0p + (size_t)128 * K;
  const int wl = wv * 512;

  const int x = ((l15 >> 1) & 3) << 3;
  const int aoff = (wmL + l15) * 32 + ((kg * 8) ^ x);
  const int boff = (wnL + l15) * 32 + ((kg * 8) ^ x);

  f32x4 acc[8][4];
#pragma unroll
  for (int i = 0; i < 8; ++i)
#pragma unroll
    for (int j = 0; j < 4; ++j) acc[i][j] = (f32x4){0.f, 0.f, 0.f, 0.f};

  if constexpr (A_F32) {
    ISSUE_A32(0, 0); STAGE_B(0); ISSUE_A32(1, 1); STAGE_B(1); STAGE_B(2);
    WRITE_A32(0);
    STEP_WAIT("vmcnt(8) lgkmcnt(0)")
#pragma unroll 1
    for (int sb = 0; sb < 28; sb += 4) {
      G32_STEP(sb + 0, 0, 0, 1, 1, 1);
      STEP_WAIT("vmcnt(8) lgkmcnt(0)")
      G32_STEP(sb + 1, 1, 1, 1, 1, 1);
      STEP_WAIT("vmcnt(8) lgkmcnt(0)")
      G32_STEP(sb + 2, 0, 2, 1, 1, 1);
      STEP_WAIT("vmcnt(8) lgkmcnt(0)")
      G32_STEP(sb + 3, 1, 3, 1, 1, 1);
      STEP_WAIT("vmcnt(8) lgkmcnt(0)")
    }
    G32_STEP(28, 0, 0, 1, 1, 1);
    STEP_WAIT("vmcnt(8) lgkmcnt(0)")
    G32_STEP(29, 1, 1, 1, 0, 1);  // issues A(31); writes A(30)
    STEP_WAIT("vmcnt(8) lgkmcnt(0)")
    G32_STEP(30, 0, 2, 0, 0, 1);  // writes A(31); compiler wait drains all
    STEP_WAIT("vmcnt(0) lgkmcnt(0)")
    G32_STEP(31, 1, 3, 0, 0, 0);
  } else {
    STAGE_A(0); STAGE_B(0); STAGE_A(1); STAGE_B(1); STAGE_A(2); STAGE_B(2);
    STEP_WAIT("vmcnt(8)")
    for (int s = 0; s < 29; ++s) {
      GEMM_STEP(s, 1);
      STEP_WAIT("vmcnt(8)")
    }
    GEMM_STEP(29, 0);
    STEP_WAIT("vmcnt(4)")
    GEMM_STEP(30, 0);
    STEP_WAIT("vmcnt(0)")
    GEMM_STEP(31, 0);
  }

#pragma unroll
  for (int mi = 0; mi < 8; ++mi) {
#pragma unroll
    for (int ni = 0; ni < 4; ++ni) {
      int col = n0 + wnL + ni * 16 + l15;
      float bcol = bias[col];
#pragma unroll
      for (int r = 0; r < 4; ++r) {
        int row = m0 + wmL + mi * 16 + kg * 4 + r;
        float v = acc[mi][ni][r] + bcol;
        if constexpr (QSCALE) v *= QK_SCALE;
        if constexpr (OUT_F32) {
          ((float*)Cv)[(size_t)row * N + col] = v;
        } else {
          // head-blocked store: [(b*16+h)][t][d]
          int t = row >> 6, bb = row & 63, hh = col >> 6, dd = col & 63;
          ((unsigned short*)Cv)[(size_t)((bb * 16 + hh) * 256 + t) * 64 + dd] = f2b(v);
        }
      }
    }
  }
}

// ---------------------------------------------------------------------------
// MFMA attention per (b,h). q/k/v/comb HEAD-BLOCKED [(b*16+h)][t][d];
// 8 waves x 32 t-rows, strip-merged. R19: softmax in EXP2 DOMAIN (log2e
// folded into the q-projection scale) via compiler-emitted exp2f; packing
// stays pack2/f2b (proven). T13 defer-rescale (THR=8, now log2 units ->
// P bounded by 2^8). combined = attn + g1[t>>2]*bw[b]*attn_pre (g0+g1==1).
// ---------------------------------------------------------------------------
__global__ __launch_bounds__(512) void attn_kernel(
    const unsigned short* __restrict__ qb, const unsigned short* __restrict__ kb,
    const unsigned short* __restrict__ vb, const float* __restrict__ prefix,
    const float* __restrict__ bw, const float* __restrict__ g1,
    unsigned short* __restrict__ comb) {
  const int b = blockIdx.x, h = blockIdx.y;
  __shared__ __attribute__((aligned(16))) unsigned short Kl[256][64];
  __shared__ __attribute__((aligned(16))) unsigned short Vt[64 * 256];
  __shared__ __attribute__((aligned(16))) unsigned short PKl[16][64];
  __shared__ __attribute__((aligned(16))) unsigned short PVt[64][32];
  __shared__ __attribute__((aligned(16))) unsigned short Plds[8][16][40];
  unsigned short* Cb = &Kl[0][0];
  const int tid = threadIdx.x;
  const int wv = tid >> 6, lane = tid & 63;
  const size_t slab = (size_t)(b * NH + h) * 16384;

#pragma unroll
  for (int it = 0; it < 4; ++it) {
    int cid = tid + it * 512;
    int j = cid >> 3, c = cid & 7;
    gl_lds16(kb + slab + (size_t)j * 64 + ((c ^ (j & 7)) << 3),
             &Kl[0][0] + (size_t)(it * 512 + wv * 64) * 8);
    ushort8 vv = *(const ushort8*)(vb + slab + (size_t)j * 64 + (c << 3));
#pragma unroll
    for (int i = 0; i < 8; ++i) {
      int gran = (j >> 3) ^ i ^ c;
      Vt[(c * 8 + i) * 256 + gran * 8 + (j & 7)] = vv[i];
    }
  }
  if (tid < 256) {
    int arr = tid >> 7, cid = tid & 127;
    int sp = cid >> 3, c = cid & 7;
    const float* src = prefix + ((size_t)(b * 2 + arr) * PP + sp) * EMB + h * HD + c * 8;
    float4v v0 = *(const float4v*)src;
    float4v v1 = *(const float4v*)(src + 4);
    if (arr == 0) {
      ushort8 o = {f2b(v0[0]), f2b(v0[1]), f2b(v0[2]), f2b(v0[3]),
                   f2b(v1[0]), f2b(v1[1]), f2b(v1[2]), f2b(v1[3])};
      *(ushort8*)&PKl[sp][((c ^ (sp & 7)) << 3)] = o;
    } else {
#pragma unroll
      for (int i = 0; i < 8; ++i)
        PVt[c * 8 + i][sp] = f2b(i < 4 ? v0[i] : v1[i - 4]);
    }
  } else if (tid < 384) {
    int cid = tid - 256;
    *(ushort8*)&PVt[cid >> 1][16 + (cid & 1) * 8] = (ushort8){0, 0, 0, 0, 0, 0, 0, 0};
  }
  __syncthreads();

  const int l15 = lane & 15, g = lane >> 4;
  const int swl = l15 & 7;
  const float bwb = bw[b];
  unsigned short(&Pw)[16][40] = Plds[wv];

  const int t0 = wv * 32 + l15;
  const size_t qbase = slab + (size_t)t0 * 64;
  bf16x8 qf[2][2];
  qf[0][0] = *(const bf16x8*)(qb + qbase + g * 8);
  qf[0][1] = *(const bf16x8*)(qb + qbase + 32 + g * 8);
  qf[1][0] = *(const bf16x8*)(qb + qbase + 1024 + g * 8);
  qf[1][1] = *(const bf16x8*)(qb + qbase + 1024 + 32 + g * 8);

  f32x4 O[2][4];
#pragma unroll
  for (int st = 0; st < 2; ++st)
#pragma unroll
    for (int dt = 0; dt < 4; ++dt) O[st][dt] = (f32x4){0.f, 0.f, 0.f, 0.f};
  float m[2] = {-3.0e38f, -3.0e38f}, l[2] = {0.f, 0.f};

#pragma unroll
  for (int ch = 0; ch < 8; ++ch) {
    const int rA = ch * 32 + l15, rB = rA + 16;
    bf16x8 ka0 = *(const bf16x8*)&Kl[rA][((g ^ swl) << 3)];
    bf16x8 ka1 = *(const bf16x8*)&Kl[rA][(((4 + g) ^ swl) << 3)];
    bf16x8 kb0 = *(const bf16x8*)&Kl[rB][((g ^ swl) << 3)];
    bf16x8 kb1 = *(const bf16x8*)&Kl[rB][(((4 + g) ^ swl) << 3)];
    f32x4 s[2][2];
#pragma unroll
    for (int st = 0; st < 2; ++st) {
      s[st][0] = (f32x4){0.f, 0.f, 0.f, 0.f};
      s[st][1] = (f32x4){0.f, 0.f, 0.f, 0.f};
      s[st][0] = mfma16(ka0, qf[st][0], s[st][0]);
      s[st][0] = mfma16(ka1, qf[st][1], s[st][0]);
      s[st][1] = mfma16(kb0, qf[st][0], s[st][1]);
      s[st][1] = mfma16(kb1, qf[st][1], s[st][1]);
    }
    bf16x8 pf[2];
#pragma unroll
    for (int st = 0; st < 2; ++st) {
      f32x4 sa = s[st][0], sb = s[st][1];
      float mx = fmaxf(fmaxf(fmaxf(sa[0], sa[1]), fmaxf(sa[2], sa[3])),
                       fmaxf(fmaxf(sb[0], sb[1]), fmaxf(sb[2], sb[3])));
      mx = fmaxf(mx, __shfl_xor(mx, 16));
      mx = fmaxf(mx, __shfl_xor(mx, 32));
      // T13 defer-rescale (log2 units): skip when all rows grew <= 8
      if (__ballot(mx > m[st] + 8.0f) != 0ull) {
        float mn = fmaxf(m[st], mx);
        float f = exp2s(m[st] - mn);
        m[st] = mn;
        l[st] *= f;
#pragma unroll
        for (int dt = 0; dt < 4; ++dt)
#pragma unroll
          for (int r = 0; r < 4; ++r) O[st][dt][r] *= f;
      }
      float pA[4], pB[4];
#pragma unroll
      for (int r = 0; r < 4; ++r) {
        pA[r] = exp2s(sa[r] - m[st]);
        pB[r] = exp2s(sb[r] - m[st]);
      }
      uint2v wa = {pack2(pA[0], pA[1]), pack2(pA[2], pA[3])};
      uint2v wb2 = {pack2(pB[0], pB[1]), pack2(pB[2], pB[3])};
      *(uint2v*)&Pw[l15][g * 4] = wa;
      *(uint2v*)&Pw[l15][16 + g * 4] = wb2;
      // l accumulates the ROUNDED p so normalization compensates quantization
      float sloc = b2f((unsigned short)(wa[0] & 0xffff)) + b2f((unsigned short)(wa[0] >> 16)) +
                   b2f((unsigned short)(wa[1] & 0xffff)) + b2f((unsigned short)(wa[1] >> 16)) +
                   b2f((unsigned short)(wb2[0] & 0xffff)) + b2f((unsigned short)(wb2[0] >> 16)) +
                   b2f((unsigned short)(wb2[1] & 0xffff)) + b2f((unsigned short)(wb2[1] >> 16));
      l[st] += sloc;
      // read own B-frag before next strip overwrites the tile (in-order DS)
      pf[st] = *(const bf16x8*)&Pw[l15][g * 8];
    }
#pragma unroll
    for (int dt = 0; dt < 4; ++dt) {
      const int drow = dt * 16 + l15;
      const int gran = (ch * 4 + g) ^ (drow & 7) ^ (drow >> 3);
      bf16x8 vf = *(const bf16x8*)&Vt[drow * 256 + gran * 8];
      O[0][dt] = mfma16(vf, pf[0], O[0][dt]);
      O[1][dt] = mfma16(vf, pf[1], O[1][dt]);
    }
  }

#pragma unroll
  for (int st = 0; st < 2; ++st) {
    float lf = l[st];
    lf += __shfl_xor(lf, 16);
    lf += __shfl_xor(lf, 32);
    float inv = 1.0f / lf;
#pragma unroll
    for (int dt = 0; dt < 4; ++dt)
#pragma unroll
      for (int r = 0; r < 4; ++r) O[st][dt][r] *= inv;
  }

  // prefix attention (s=16 zero-padded to 32), scaled by g1*bw/sum
  {
    bf16x8 pk0 = *(const bf16x8*)&PKl[l15][((g ^ swl) << 3)];
    bf16x8 pk1 = *(const bf16x8*)&PKl[l15][(((4 + g) ^ swl) << 3)];
    bf16x8 ppf[2];
#pragma unroll
    for (int st = 0; st < 2; ++st) {
      f32x4 sp4 = (f32x4){0.f, 0.f, 0.f, 0.f};
      sp4 = mfma16(pk0, qf[st][0], sp4);
      sp4 = mfma16(pk1, qf[st][1], sp4);
      float pm = fmaxf(fmaxf(sp4[0], sp4[1]), fmaxf(sp4[2], sp4[3]));
      pm = fmaxf(pm, __shfl_xor(pm, 16));
      pm = fmaxf(pm, __shfl_xor(pm, 32));
      float pe[4], pl = 0.f;
#pragma unroll
      for (int r = 0; r < 4; ++r) {
        pe[r] = exp2s(sp4[r] - pm);
        pl += pe[r];
      }
      pl += __shfl_xor(pl, 16);
      pl += __shfl_xor(pl, 32);
      float cpre = g1[(t0 + 16 * st) >> 2] * bwb / pl;
#pragma unroll
      for (int r = 0; r < 4; ++r) pe[r] *= cpre;
      *(uint2v*)&Pw[l15][g * 4] = (uint2v){pack2(pe[0], pe[1]), pack2(pe[2], pe[3])};
      *(uint2v*)&Pw[l15][16 + g * 4] = (uint2v){0u, 0u};
      ppf[st] = *(const bf16x8*)&Pw[l15][g * 8];
    }
#pragma unroll
    for (int dt = 0; dt < 4; ++dt) {
      bf16x8 pvf = *(const bf16x8*)&PVt[dt * 16 + l15][g * 8];
      O[0][dt] = mfma16(pvf, ppf[0], O[0][dt]);
      O[1][dt] = mfma16(pvf, ppf[1], O[1][dt]);
    }
  }

  __syncthreads();  // all waves done reading Kl before bounce overlays it
#pragma unroll
  for (int st = 0; st < 2; ++st) {
    int t = wv * 32 + st * 16 + l15;
#pragma unroll
    for (int dt = 0; dt < 4; ++dt) {
#pragma unroll
      for (int u = 0; u < 2; ++u) {
        unsigned int pw = pack2(O[st][dt][2 * u], O[st][dt][2 * u + 1]);
        int d = dt * 16 + g * 4 + 2 * u;
        *(unsigned int*)&Cb[t * 64 + (((d >> 3) ^ (t & 7)) << 3) + (d & 7)] = pw;
      }
    }
  }
  __syncthreads();
#pragma unroll
  for (int it = 0; it < 4; ++it) {
    int cid = tid + it * 512;
    int j = cid >> 3, c = cid & 7;
    ushort8 row = *(const ushort8*)&Cb[j * 64 + ((c ^ (j & 7)) << 3)];
    *(ushort8*)(comb + slab + (size_t)j * 64 + (c << 3)) = row;
  }
}

// ---------------------------------------------------------------------------
extern "C" void kernel_launch(void* const* d_in, const int* in_sizes, int n_in,
                              void* d_out, int out_size, void* d_ws, size_t ws_size,
                              hipStream_t stream) {
  const float* query = (const float*)d_in[1];
  const float* key = (const float*)d_in[2];
  const float* value = (const float*)d_in[3];
  const float* prefix = (const float*)d_in[4];
  const float* bw = (const float*)d_in[5];
  const float* feat = (const float*)d_in[6];
  const float* noise = (const float*)d_in[7];
  const float* ipw = (const float*)d_in[8];
  const float* ipb = (const float*)d_in[9];
  const float* outw = (const float*)d_in[10];
  const float* outb = (const float*)d_in[11];
  const float* gw = (const float*)d_in[12];
  const float* gb = (const float*)d_in[13];
  float* out = (float*)d_out;

  char* ws = (char*)d_ws;
  const size_t MATB = (size_t)16384 * 1024;  // elements per [16384,1024] matrix
  unsigned short* qb = (unsigned short*)ws;
  unsigned short* kb = qb + MATB;
  unsigned short* vb = kb + MATB;
  unsigned short* cb = vb + MATB;            // attn output (head-blocked)
  unsigned short* wip = cb + MATB;           // bf16 in_proj_w [3072,1024]
  unsigned short* wo = wip + (size_t)3072 * 1024;  // bf16 out_w [1024,1024]
  float* g1 = (float*)(wo + (size_t)1024 * 1024);

  // gate + both weight casts in ONE dispatch
  fused_pre_kernel<<<2112, 256, 0, stream>>>(ipw, wip, outw, wo, feat, gw, gb,
                                             noise, g1);

  // projections read f32 inputs directly (f2b write-side staging, lead-2,
  // rolled main loop) — R13/R18-proven
  gemm256_kernel<0, 1, 0, 1><<<256, 512, 0, stream>>>(query, wip, ipb, qb);
  gemm256_kernel<0, 0, 0, 1><<<256, 512, 0, stream>>>(key, wip + (size_t)1024 * 1024, ipb + 1024, kb);
  gemm256_kernel<0, 0, 0, 1><<<256, 512, 0, stream>>>(value, wip + (size_t)2048 * 1024, ipb + 2048, vb);

  attn_kernel<<<dim3(64, 16), 512, 0, stream>>>(qb, kb, vb, prefix, bw, g1, cb);

  // out-projection reads head-blocked bf16 attn output (proven gl_lds path)
  gemm256_kernel<1, 0, 1, 0><<<256, 512, 0, stream>>>(cb, wo, outb, out);
}